// Round 1
// baseline (13001.994 us; speedup 1.0000x reference)
//
#include <hip/hip_runtime.h>
#include <math.h>

#define D_MODEL 512
#define NHEAD   8
#define DKH     64
#define NLAYER  6
#define DFF_    2048
#define VOCAB   32000
#define BATCH   2
#define SEQ     2048
#define NTOK    (BATCH*SEQ)
#define PAD_ID  1

// ------------------------------------------------------------------ embed
__global__ __launch_bounds__(256) void embed_kernel(
    const int* __restrict__ tok, const float* __restrict__ emb,
    const float* __restrict__ pe, float* __restrict__ out)
{
  const int total = NTOK * D_MODEL;
  for (int i = blockIdx.x * 256 + threadIdx.x; i < total; i += gridDim.x * 256) {
    int t = i >> 9;            // / D_MODEL
    int d = i & 511;           // % D_MODEL
    int s = t & (SEQ - 1);     // position within sequence
    out[i] = emb[(size_t)tok[t] * D_MODEL + d] + pe[(size_t)s * D_MODEL + d];
  }
}

// ------------------------------------------------------------------ layernorm (one block per row, D=512)
__global__ __launch_bounds__(256) void ln_kernel(
    const float* __restrict__ x, const float* __restrict__ g,
    const float* __restrict__ bb, float* __restrict__ y)
{
  __shared__ float red[8];
  const size_t row = blockIdx.x;
  const float* xr = x + row * D_MODEL;
  float* yr = y + row * D_MODEL;
  const int t = threadIdx.x;
  float a0 = xr[t], a1 = xr[t + 256];
  float s = a0 + a1;
  #pragma unroll
  for (int o = 32; o > 0; o >>= 1) s += __shfl_down(s, o, 64);
  int wv = t >> 6, ln = t & 63;
  if (ln == 0) red[wv] = s;
  __syncthreads();
  if (t == 0) red[4] = red[0] + red[1] + red[2] + red[3];
  __syncthreads();
  float mean = red[4] * (1.0f / D_MODEL);
  float d0 = a0 - mean, d1 = a1 - mean;
  float vs = d0 * d0 + d1 * d1;
  #pragma unroll
  for (int o = 32; o > 0; o >>= 1) vs += __shfl_down(vs, o, 64);
  if (ln == 0) red[wv] = vs;
  __syncthreads();
  if (t == 0) red[5] = red[0] + red[1] + red[2] + red[3];
  __syncthreads();
  float inv = rsqrtf(red[5] * (1.0f / D_MODEL) + 1e-5f);
  yr[t]       = d0 * inv * g[t]       + bb[t];
  yr[t + 256] = d1 * inv * g[t + 256] + bb[t + 256];
}

// ------------------------------------------------------------------ f32 GEMM: C = A[M,K] @ W[K,N] + bias (+res) (+relu)
// 64x64 tile, BK=16, 256 threads, 4x4 micro-tile. blockIdx.z batches over
// contiguous weight/bias/output slices (QKV fused).
template<bool RELU, bool RES>
__global__ __launch_bounds__(256) void gemm_kernel(
    const float* __restrict__ A, const float* __restrict__ W,
    const float* __restrict__ bias, const float* res, float* C,
    int M, int N, int K,
    long long wStride, long long bStride, long long cStride)
{
  __shared__ float As[16][68];   // [k][m], row stride 68 floats = 272B (16B aligned)
  __shared__ float Bs[16][64];   // [k][n]
  const int z = blockIdx.z;
  W    += (size_t)z * wStride;
  bias += (size_t)z * bStride;
  C    += (size_t)z * cStride;
  const int bm = blockIdx.y * 64, bn = blockIdx.x * 64;
  const int tid = threadIdx.x, tx = tid & 15, ty = tid >> 4;
  const int ar = tid >> 2, ak = (tid & 3) * 4;   // A loader: row, k-offset
  const int bk = tid >> 4, bc = (tid & 15) * 4;  // B loader: k-row, col
  const float* aPtr = A + (size_t)(bm + ar) * K + ak;
  const float* bPtr = W + (size_t)bk * N + bn + bc;
  float acc[4][4] = {};
  for (int k0 = 0; k0 < K; k0 += 16) {
    float4 av = *(const float4*)aPtr;
    float4 bv = *(const float4*)bPtr;
    As[ak + 0][ar] = av.x;
    As[ak + 1][ar] = av.y;
    As[ak + 2][ar] = av.z;
    As[ak + 3][ar] = av.w;
    *(float4*)&Bs[bk][bc] = bv;
    __syncthreads();
    #pragma unroll
    for (int kk = 0; kk < 16; ++kk) {
      float4 a4 = *(const float4*)&As[kk][ty * 4];
      float4 b4 = *(const float4*)&Bs[kk][tx * 4];
      float a[4] = {a4.x, a4.y, a4.z, a4.w};
      float b[4] = {b4.x, b4.y, b4.z, b4.w};
      #pragma unroll
      for (int i = 0; i < 4; ++i)
        #pragma unroll
        for (int j = 0; j < 4; ++j)
          acc[i][j] = fmaf(a[i], b[j], acc[i][j]);
    }
    __syncthreads();
    aPtr += 16;
    bPtr += (size_t)16 * N;
  }
  #pragma unroll
  for (int i = 0; i < 4; ++i) {
    const size_t r = (size_t)(bm + ty * 4 + i);
    const size_t off = r * N + bn + tx * 4;
    float vj[4];
    #pragma unroll
    for (int j = 0; j < 4; ++j) {
      float u = acc[i][j] + bias[bn + tx * 4 + j];
      if (RES) u += res[off + j];
      if (RELU) u = fmaxf(u, 0.0f);
      vj[j] = u;
    }
    float4 o; o.x = vj[0]; o.y = vj[1]; o.z = vj[2]; o.w = vj[3];
    *(float4*)(C + off) = o;
  }
}

// ------------------------------------------------------------------ fused flash-style attention, f32
// grid (S/64, H, B), 256 threads. 64 q-rows x 64 k-cols per tile, dk=64.
// LDS: QsT + KP(K^T reused as P^T) + Vs = 52.5 KB.
template<bool CAUSAL>
__global__ __launch_bounds__(256) void attn_kernel(
    const float* __restrict__ Q, const float* __restrict__ Kg,
    const float* __restrict__ Vg, const int* __restrict__ ktok,
    float* __restrict__ O)
{
  __shared__ float QsT[64][68];  // [d][q-row], pre-scaled by 1/sqrt(dk)
  __shared__ float KP[64][68];   // K^T: [d][k-col]; reused as P^T: [k][q-row]
  __shared__ float Vs[64][68];   // [k][d]
  __shared__ int padA[64];
  const int qt = blockIdx.x * 64;
  const int h = blockIdx.y;
  const int b = blockIdx.z;
  const int tid = threadIdx.x, tx = tid & 15, ty = tid >> 4;
  const size_t hoff = (size_t)h * DKH;

  #pragma unroll
  for (int it = 0; it < 4; ++it) {
    int idx = it * 256 + tid;
    int r = idx >> 4, c4 = (idx & 15) * 4;
    float4 v = *(const float4*)(Q + ((size_t)(b * SEQ + qt + r)) * D_MODEL + hoff + c4);
    QsT[c4 + 0][r] = v.x * 0.125f;
    QsT[c4 + 1][r] = v.y * 0.125f;
    QsT[c4 + 2][r] = v.z * 0.125f;
    QsT[c4 + 3][r] = v.w * 0.125f;
  }

  float acc[4][4] = {};
  float mrow[4] = {-1e30f, -1e30f, -1e30f, -1e30f};
  float lrow[4] = {0.f, 0.f, 0.f, 0.f};

  const int nt = CAUSAL ? (qt / 64 + 1) : (SEQ / 64);
  for (int kt = 0; kt < nt; ++kt) {
    const int kpos0 = kt * 64;
    __syncthreads();   // previous tile's KP/Vs consumers done
    #pragma unroll
    for (int it = 0; it < 4; ++it) {
      int idx = it * 256 + tid;
      int r = idx >> 4, c4 = (idx & 15) * 4;
      size_t rowoff = ((size_t)(b * SEQ + kpos0 + r)) * D_MODEL + hoff + c4;
      float4 kv = *(const float4*)(Kg + rowoff);
      KP[c4 + 0][r] = kv.x;
      KP[c4 + 1][r] = kv.y;
      KP[c4 + 2][r] = kv.z;
      KP[c4 + 3][r] = kv.w;
      float4 vv = *(const float4*)(Vg + rowoff);
      *(float4*)&Vs[r][c4] = vv;
    }
    if (tid < 64) padA[tid] = (ktok[b * SEQ + kpos0 + tid] != PAD_ID) ? 1 : 0;
    __syncthreads();

    // scores S = (Q/8) @ K^T
    float s[4][4] = {};
    #pragma unroll 8
    for (int d = 0; d < 64; ++d) {
      float4 a4 = *(const float4*)&QsT[d][ty * 4];
      float4 b4 = *(const float4*)&KP[d][tx * 4];
      float a[4] = {a4.x, a4.y, a4.z, a4.w};
      float bb2[4] = {b4.x, b4.y, b4.z, b4.w};
      #pragma unroll
      for (int i = 0; i < 4; ++i)
        #pragma unroll
        for (int j = 0; j < 4; ++j)
          s[i][j] = fmaf(a[i], bb2[j], s[i][j]);
    }

    int pok[4];
    #pragma unroll
    for (int j = 0; j < 4; ++j) pok[j] = padA[tx * 4 + j];

    float p[4][4];
    float scl[4];
    #pragma unroll
    for (int i = 0; i < 4; ++i) {
      const int qg = qt + ty * 4 + i;
      float mloc = -1e30f;
      #pragma unroll
      for (int j = 0; j < 4; ++j) {
        const int kg2 = kpos0 + tx * 4 + j;
        bool ok = (pok[j] != 0) && (!CAUSAL || (kg2 <= qg));
        s[i][j] = ok ? s[i][j] : -1e30f;
        mloc = fmaxf(mloc, s[i][j]);
      }
      #pragma unroll
      for (int o = 1; o < 16; o <<= 1) mloc = fmaxf(mloc, __shfl_xor(mloc, o, 16));
      float mn = fmaxf(mrow[i], mloc);
      scl[i] = __expf(mrow[i] - mn);
      mrow[i] = mn;
      float rs = 0.f;
      #pragma unroll
      for (int j = 0; j < 4; ++j) {
        float pv = __expf(s[i][j] - mn);
        p[i][j] = pv;
        rs += pv;
      }
      #pragma unroll
      for (int o = 1; o < 16; o <<= 1) rs += __shfl_xor(rs, o, 16);
      lrow[i] = lrow[i] * scl[i] + rs;
    }
    __syncthreads();  // everyone done reading KP as K^T
    #pragma unroll
    for (int i = 0; i < 4; ++i) {
      #pragma unroll
      for (int j = 0; j < 4; ++j) {
        KP[tx * 4 + j][ty * 4 + i] = p[i][j];   // store P^T
        acc[i][j] *= scl[i];
      }
    }
    __syncthreads();
    // O += P @ V
    #pragma unroll 8
    for (int kk = 0; kk < 64; ++kk) {
      float4 a4 = *(const float4*)&KP[kk][ty * 4];
      float4 b4 = *(const float4*)&Vs[kk][tx * 4];
      float a[4] = {a4.x, a4.y, a4.z, a4.w};
      float bb2[4] = {b4.x, b4.y, b4.z, b4.w};
      #pragma unroll
      for (int i = 0; i < 4; ++i)
        #pragma unroll
        for (int j = 0; j < 4; ++j)
          acc[i][j] = fmaf(a[i], bb2[j], acc[i][j]);
    }
  }
  #pragma unroll
  for (int i = 0; i < 4; ++i) {
    float inv = 1.0f / lrow[i];
    float4 o;
    o.x = acc[i][0] * inv;
    o.y = acc[i][1] * inv;
    o.z = acc[i][2] * inv;
    o.w = acc[i][3] * inv;
    *(float4*)(O + ((size_t)(b * SEQ + qt + ty * 4 + i)) * D_MODEL + hoff + tx * 4) = o;
  }
}

// ------------------------------------------------------------------ host
extern "C" void kernel_launch(void* const* d_in, const int* in_sizes, int n_in,
                              void* d_out, int out_size, void* d_ws, size_t ws_size,
                              hipStream_t stream)
{
  const int*   src        = (const int*)  d_in[0];
  const int*   tgt        = (const int*)  d_in[1];
  const float* src_emb    = (const float*)d_in[2];
  const float* tgt_emb    = (const float*)d_in[3];
  const float* pe         = (const float*)d_in[4];
  const float* enc_attn_w = (const float*)d_in[5];
  const float* enc_attn_b = (const float*)d_in[6];
  const float* enc_ff_w1  = (const float*)d_in[7];
  const float* enc_ff_b1  = (const float*)d_in[8];
  const float* enc_ff_w2  = (const float*)d_in[9];
  const float* enc_ff_b2  = (const float*)d_in[10];
  const float* enc_ln_g   = (const float*)d_in[11];
  const float* enc_ln_bb  = (const float*)d_in[12];
  const float* dec_self_w = (const float*)d_in[13];
  const float* dec_self_b = (const float*)d_in[14];
  const float* dec_src_w  = (const float*)d_in[15];
  const float* dec_src_b  = (const float*)d_in[16];
  const float* dec_ff_w1  = (const float*)d_in[17];
  const float* dec_ff_b1  = (const float*)d_in[18];
  const float* dec_ff_w2  = (const float*)d_in[19];
  const float* dec_ff_b2  = (const float*)d_in[20];
  const float* dec_ln_g   = (const float*)d_in[21];
  const float* dec_ln_bb  = (const float*)d_in[22];
  const float* fin_ln_g   = (const float*)d_in[23];
  const float* fin_ln_b   = (const float*)d_in[24];
  const float* fc_w       = (const float*)d_in[25];
  const float* fc_b       = (const float*)d_in[26];
  float* out = (float*)d_out;

  float* ws = (float*)d_ws;
  const size_t TD = (size_t)NTOK * D_MODEL;      // 2,097,152 floats
  float* xe = ws;                                 // encoder x / memory
  float* yd = ws + TD;                            // decoder x
  float* x2 = ws + 2 * TD;                        // LN output
  float* qb = ws + 3 * TD;
  float* kb = ws + 4 * TD;                        // q,k,v contiguous for batched GEMM
  float* vb = ws + 5 * TD;
  float* ao = ws + 6 * TD;                        // attention output (heads concat)
  float* hb = ws + 7 * TD;                        // FF hidden [NTOK, DFF]
  const size_t needBytes = (7 * TD + (size_t)NTOK * DFF_) * sizeof(float);
  if (ws_size < needBytes) hb = out;              // fallback: d_out as FF scratch (out written last)

  const long long DD = (long long)D_MODEL * D_MODEL;
  dim3 blk(256);
  dim3 gridProj(D_MODEL / 64, NTOK / 64);         // (8, 64)
  dim3 gridFF1(DFF_ / 64, NTOK / 64);             // (32, 64)
  dim3 gridFC(VOCAB / 64, NTOK / 64);             // (500, 64)
  dim3 gridAttn(SEQ / 64, NHEAD, BATCH);          // (32, 8, 2)

  // ---------------- encoder ----------------
  embed_kernel<<<dim3(2048), blk, 0, stream>>>(src, src_emb, pe, xe);
  for (int l = 0; l < NLAYER; ++l) {
    const float* Wl = enc_attn_w + (size_t)l * 4 * DD;
    const float* bl = enc_attn_b + (size_t)l * 4 * D_MODEL;
    ln_kernel<<<dim3(NTOK), blk, 0, stream>>>(xe, enc_ln_g + (size_t)(l * 2 + 0) * D_MODEL,
                                              enc_ln_bb + (size_t)(l * 2 + 0) * D_MODEL, x2);
    gemm_kernel<false, false><<<dim3(D_MODEL / 64, NTOK / 64, 3), blk, 0, stream>>>(
        x2, Wl, bl, nullptr, qb, NTOK, D_MODEL, D_MODEL, DD, D_MODEL, (long long)TD);
    attn_kernel<false><<<gridAttn, blk, 0, stream>>>(qb, kb, vb, src, ao);
    gemm_kernel<false, true><<<gridProj, blk, 0, stream>>>(
        ao, Wl + 3 * DD, bl + 3 * D_MODEL, xe, xe, NTOK, D_MODEL, D_MODEL, 0, 0, 0);
    ln_kernel<<<dim3(NTOK), blk, 0, stream>>>(xe, enc_ln_g + (size_t)(l * 2 + 1) * D_MODEL,
                                              enc_ln_bb + (size_t)(l * 2 + 1) * D_MODEL, x2);
    gemm_kernel<true, false><<<gridFF1, blk, 0, stream>>>(
        x2, enc_ff_w1 + (size_t)l * D_MODEL * DFF_, enc_ff_b1 + (size_t)l * DFF_, nullptr, hb,
        NTOK, DFF_, D_MODEL, 0, 0, 0);
    gemm_kernel<false, true><<<gridProj, blk, 0, stream>>>(
        hb, enc_ff_w2 + (size_t)l * DFF_ * D_MODEL, enc_ff_b2 + (size_t)l * D_MODEL, xe, xe,
        NTOK, D_MODEL, DFF_, 0, 0, 0);
  }

  // ---------------- decoder ----------------
  embed_kernel<<<dim3(2048), blk, 0, stream>>>(tgt, tgt_emb, pe, yd);
  for (int l = 0; l < NLAYER; ++l) {
    const float* Ws  = dec_self_w + (size_t)l * 4 * DD;
    const float* bs  = dec_self_b + (size_t)l * 4 * D_MODEL;
    const float* Wc  = dec_src_w + (size_t)l * 4 * DD;
    const float* bcb = dec_src_b + (size_t)l * 4 * D_MODEL;
    // self-attention (causal + tgt pad mask)
    ln_kernel<<<dim3(NTOK), blk, 0, stream>>>(yd, dec_ln_g + (size_t)(l * 3 + 0) * D_MODEL,
                                              dec_ln_bb + (size_t)(l * 3 + 0) * D_MODEL, x2);
    gemm_kernel<false, false><<<dim3(D_MODEL / 64, NTOK / 64, 3), blk, 0, stream>>>(
        x2, Ws, bs, nullptr, qb, NTOK, D_MODEL, D_MODEL, DD, D_MODEL, (long long)TD);
    attn_kernel<true><<<gridAttn, blk, 0, stream>>>(qb, kb, vb, tgt, ao);
    gemm_kernel<false, true><<<gridProj, blk, 0, stream>>>(
        ao, Ws + 3 * DD, bs + 3 * D_MODEL, yd, yd, NTOK, D_MODEL, D_MODEL, 0, 0, 0);
    // cross-attention (q from y2, k/v from encoder memory, src pad mask)
    ln_kernel<<<dim3(NTOK), blk, 0, stream>>>(yd, dec_ln_g + (size_t)(l * 3 + 1) * D_MODEL,
                                              dec_ln_bb + (size_t)(l * 3 + 1) * D_MODEL, x2);
    gemm_kernel<false, false><<<gridProj, blk, 0, stream>>>(
        x2, Wc, bcb, nullptr, qb, NTOK, D_MODEL, D_MODEL, 0, 0, 0);
    gemm_kernel<false, false><<<dim3(D_MODEL / 64, NTOK / 64, 2), blk, 0, stream>>>(
        xe, Wc + DD, bcb + D_MODEL, nullptr, kb, NTOK, D_MODEL, D_MODEL, DD, D_MODEL, (long long)TD);
    attn_kernel<false><<<gridAttn, blk, 0, stream>>>(qb, kb, vb, src, ao);
    gemm_kernel<false, true><<<gridProj, blk, 0, stream>>>(
        ao, Wc + 3 * DD, bcb + 3 * D_MODEL, yd, yd, NTOK, D_MODEL, D_MODEL, 0, 0, 0);
    // feed-forward
    ln_kernel<<<dim3(NTOK), blk, 0, stream>>>(yd, dec_ln_g + (size_t)(l * 3 + 2) * D_MODEL,
                                              dec_ln_bb + (size_t)(l * 3 + 2) * D_MODEL, x2);
    gemm_kernel<true, false><<<gridFF1, blk, 0, stream>>>(
        x2, dec_ff_w1 + (size_t)l * D_MODEL * DFF_, dec_ff_b1 + (size_t)l * DFF_, nullptr, hb,
        NTOK, DFF_, D_MODEL, 0, 0, 0);
    gemm_kernel<false, true><<<gridProj, blk, 0, stream>>>(
        hb, dec_ff_w2 + (size_t)l * DFF_ * D_MODEL, dec_ff_b2 + (size_t)l * D_MODEL, yd, yd,
        NTOK, D_MODEL, DFF_, 0, 0, 0);
  }

  // ---------------- head ----------------
  ln_kernel<<<dim3(NTOK), blk, 0, stream>>>(yd, fin_ln_g, fin_ln_b, x2);
  gemm_kernel<false, false><<<gridFC, blk, 0, stream>>>(
      x2, fc_w, fc_b, nullptr, out, NTOK, VOCAB, D_MODEL, 0, 0, 0);

  (void)in_sizes; (void)n_in; (void)out_size; (void)ws_size;
}

// Round 2
// 3647.836 us; speedup vs baseline: 3.5643x; 3.5643x over previous
//
#include <hip/hip_runtime.h>
#include <math.h>

#define D_MODEL 512
#define NHEAD   8
#define NLAYER  6
#define DFF_    2048
#define VOCAB   32000
#define BATCH   2
#define SEQ     2048
#define NTOK    (BATCH*SEQ)
#define PAD_ID  1

typedef __attribute__((ext_vector_type(8))) short s16x8;
typedef __attribute__((ext_vector_type(4))) float f32x4;
typedef unsigned short u16;
typedef unsigned int   u32;

__device__ __forceinline__ u16 f2bf(float x) {
  u32 u = __builtin_bit_cast(u32, x);
  u += 0x7FFFu + ((u >> 16) & 1u);
  return (u16)(u >> 16);
}

__device__ __forceinline__ void gload16(const void* g, void* l) {
  __builtin_amdgcn_global_load_lds(
      (const __attribute__((address_space(1))) u32*)g,
      (__attribute__((address_space(3))) u32*)l, 16, 0, 0);
}

// ------------------------------------------------------------------ embed (f32 residual stream)
__global__ __launch_bounds__(256) void embed_kernel(
    const int* __restrict__ tok, const float* __restrict__ emb,
    const float* __restrict__ pe, float* __restrict__ out)
{
  const int total = NTOK * D_MODEL;
  for (int i = blockIdx.x * 256 + threadIdx.x; i < total; i += gridDim.x * 256) {
    int t = i >> 9;
    int d = i & 511;
    int s = t & (SEQ - 1);
    out[i] = emb[(size_t)tok[t] * D_MODEL + d] + pe[(size_t)s * D_MODEL + d];
  }
}

// ------------------------------------------------------------------ layernorm: f32 in -> bf16 out
__global__ __launch_bounds__(256) void ln_kernel(
    const float* __restrict__ x, const float* __restrict__ g,
    const float* __restrict__ bb, u16* __restrict__ y)
{
  __shared__ float red[8];
  const size_t row = blockIdx.x;
  const float* xr = x + row * D_MODEL;
  u16* yr = y + row * D_MODEL;
  const int t = threadIdx.x;
  float a0 = xr[t], a1 = xr[t + 256];
  float s = a0 + a1;
  #pragma unroll
  for (int o = 32; o > 0; o >>= 1) s += __shfl_down(s, o, 64);
  int wv = t >> 6, ln = t & 63;
  if (ln == 0) red[wv] = s;
  __syncthreads();
  if (t == 0) red[4] = red[0] + red[1] + red[2] + red[3];
  __syncthreads();
  float mean = red[4] * (1.0f / D_MODEL);
  float d0 = a0 - mean, d1 = a1 - mean;
  float vs = d0 * d0 + d1 * d1;
  #pragma unroll
  for (int o = 32; o > 0; o >>= 1) vs += __shfl_down(vs, o, 64);
  if (ln == 0) red[wv] = vs;
  __syncthreads();
  if (t == 0) red[5] = red[0] + red[1] + red[2] + red[3];
  __syncthreads();
  float inv = rsqrtf(red[5] * (1.0f / D_MODEL) + 1e-5f);
  yr[t]       = f2bf(d0 * inv * g[t]       + bb[t]);
  yr[t + 256] = f2bf(d1 * inv * g[t + 256] + bb[t + 256]);
}

// ------------------------------------------------------------------ f32 -> bf16 elementwise
__global__ __launch_bounds__(256) void cvtbf_kernel(
    const float* __restrict__ s, u16* __restrict__ d, int n)
{
  int i = (blockIdx.x * 256 + threadIdx.x) * 8;
  if (i >= n) return;
  float4 a = *(const float4*)&s[i];
  float4 b = *(const float4*)&s[i + 4];
  u32 p0 = (u32)f2bf(a.x) | ((u32)f2bf(a.y) << 16);
  u32 p1 = (u32)f2bf(a.z) | ((u32)f2bf(a.w) << 16);
  u32 p2 = (u32)f2bf(b.x) | ((u32)f2bf(b.y) << 16);
  u32 p3 = (u32)f2bf(b.z) | ((u32)f2bf(b.w) << 16);
  uint4 o; o.x = p0; o.y = p1; o.z = p2; o.w = p3;
  *(uint4*)&d[i] = o;
}

// ------------------------------------------------------------------ transpose+convert: src f32 [K][N] -> dst bf16 [N][K]
// grid (N/64, K/64, z)
__global__ __launch_bounds__(256) void tconv_kernel(
    const float* __restrict__ src, u16* __restrict__ dst, int K, int N)
{
  __shared__ float tile[64][65];
  const size_t z = blockIdx.z;
  src += z * (size_t)K * N;
  dst += z * (size_t)K * N;
  const int n0 = blockIdx.x * 64, k0 = blockIdx.y * 64;
  const int t = threadIdx.x;
  const int cr = t >> 4, cc = (t & 15) * 4;
  #pragma unroll
  for (int it = 0; it < 4; ++it) {
    int kr = cr + it * 16;
    float4 v = *(const float4*)&src[(size_t)(k0 + kr) * N + n0 + cc];
    tile[kr][cc] = v.x; tile[kr][cc + 1] = v.y; tile[kr][cc + 2] = v.z; tile[kr][cc + 3] = v.w;
  }
  __syncthreads();
  #pragma unroll
  for (int it = 0; it < 4; ++it) {
    int nr = cr + it * 16;
    u32 lo = (u32)f2bf(tile[cc + 0][nr]) | ((u32)f2bf(tile[cc + 1][nr]) << 16);
    u32 hi = (u32)f2bf(tile[cc + 2][nr]) | ((u32)f2bf(tile[cc + 3][nr]) << 16);
    uint2 pk; pk.x = lo; pk.y = hi;
    *(uint2*)&dst[(size_t)(n0 + nr) * K + k0 + cc] = pk;
  }
}

// ------------------------------------------------------------------ V transpose: v [NTOK][512] bf16 -> vt [B*H][64][SEQ] bf16
// grid (SEQ/64, 1, B*H)
__global__ __launch_bounds__(256) void vtrans_kernel(
    const u16* __restrict__ v, u16* __restrict__ vt)
{
  __shared__ u16 tile[64][65];
  const int bh = blockIdx.z, s0 = blockIdx.x * 64;
  const int b = bh >> 3, h = bh & 7;
  const int t = threadIdx.x;
  const int lr = t >> 3, lc = (t & 7) * 8;
  #pragma unroll
  for (int it = 0; it < 2; ++it) {
    int srow = lr + it * 32;
    s16x8 val = *(const s16x8*)(v + (size_t)(b * SEQ + s0 + srow) * D_MODEL + h * 64 + lc);
    #pragma unroll
    for (int j = 0; j < 8; ++j) tile[srow][lc + j] = (u16)val[j];
  }
  __syncthreads();
  #pragma unroll
  for (int it = 0; it < 2; ++it) {
    int drow = lr + it * 32;
    s16x8 o;
    #pragma unroll
    for (int j = 0; j < 8; ++j) o[j] = (short)tile[lc + j][drow];
    *(s16x8*)(vt + ((size_t)bh * 64 + drow) * SEQ + s0 + lc) = o;
  }
}

// ------------------------------------------------------------------ bf16 MFMA GEMM: C[M,N] = A[M,K] @ Wt[N,K]^T + bias
// MODE 0: f32 out, 1: f32 out + res, 2: bf16 out, 3: bf16 out + relu
// 128x128 tile, BK=64, 4 waves. XOR-swizzled LDS (pre-swizzled source, swizzled read).
template<int MODE>
__global__ __launch_bounds__(256, 2) void mm_kernel(
    const u16* __restrict__ A, const u16* __restrict__ Wt,
    const float* __restrict__ bias, const float* __restrict__ res,
    void* __restrict__ Cout, int M, int N, int K,
    long long wStride, long long bStride, long long cStride)
{
  __shared__ u16 As[128 * 64];
  __shared__ u16 Bs[128 * 64];
  const int z = blockIdx.z;
  Wt   += (size_t)z * wStride;
  bias += (size_t)z * bStride;
  const int bm = blockIdx.y * 128, bn = blockIdx.x * 128;
  const int tid = threadIdx.x, lane = tid & 63, w = tid >> 6;
  const int wm = w >> 1, wn = w & 1;
  const int l15 = lane & 15, l4 = lane >> 4;
  const u16* aBase = A  + (size_t)bm * K;
  const u16* bBase = Wt + (size_t)bn * K;
  f32x4 acc[4][4] = {};

  for (int k0 = 0; k0 < K; k0 += 64) {
    #pragma unroll
    for (int i = 0; i < 4; ++i) {
      int t16 = i * 256 + tid;
      int r = t16 >> 3, sp = t16 & 7;
      int ss = (sp ^ (r & 7)) * 8;          // inverse-swizzled source k-slot
      gload16(aBase + (size_t)r * K + k0 + ss, &As[(i * 256 + w * 64) * 8]);
      gload16(bBase + (size_t)r * K + k0 + ss, &Bs[(i * 256 + w * 64) * 8]);
    }
    __syncthreads();
    #pragma unroll
    for (int ks = 0; ks < 2; ++ks) {
      s16x8 af[4], bf[4];
      #pragma unroll
      for (int mi = 0; mi < 4; ++mi) {
        int rr = wm * 64 + mi * 16 + l15;
        af[mi] = *(const s16x8*)&As[(rr << 6) + (((ks * 4 + l4) ^ (rr & 7)) << 3)];
      }
      #pragma unroll
      for (int ni = 0; ni < 4; ++ni) {
        int rr = wn * 64 + ni * 16 + l15;
        bf[ni] = *(const s16x8*)&Bs[(rr << 6) + (((ks * 4 + l4) ^ (rr & 7)) << 3)];
      }
      #pragma unroll
      for (int mi = 0; mi < 4; ++mi)
        #pragma unroll
        for (int ni = 0; ni < 4; ++ni)
          acc[mi][ni] = __builtin_amdgcn_mfma_f32_16x16x32_bf16(af[mi], bf[ni], acc[mi][ni], 0, 0, 0);
    }
    __syncthreads();
  }

  #pragma unroll
  for (int ni = 0; ni < 4; ++ni) {
    int col = bn + wn * 64 + ni * 16 + l15;
    float bb = bias[col];
    #pragma unroll
    for (int mi = 0; mi < 4; ++mi) {
      #pragma unroll
      for (int r = 0; r < 4; ++r) {
        int row = bm + wm * 64 + mi * 16 + l4 * 4 + r;
        size_t off = (size_t)z * cStride + (size_t)row * N + col;
        float v = acc[mi][ni][r] + bb;
        if (MODE == 1) v += res[(size_t)row * N + col];
        if (MODE == 3) v = fmaxf(v, 0.0f);
        if (MODE <= 1) ((float*)Cout)[off] = v;
        else           ((u16*)Cout)[off] = f2bf(v);
      }
    }
  }
}

// ------------------------------------------------------------------ flash attention, bf16 MFMA
// grid (SEQ/64, H, B), 4 waves; wave w owns q-rows [qt+16w, qt+16w+16)
template<int CAUSAL>
__global__ __launch_bounds__(256, 2) void fattn_kernel(
    const u16* __restrict__ Qg, const u16* __restrict__ Kg,
    const u16* __restrict__ Vt, const int* __restrict__ ktok,
    u16* __restrict__ Og)
{
  __shared__ u16 Ks[64 * 64];
  __shared__ u16 Vs[64 * 64];
  __shared__ u16 Ps[4 * 16 * 64];
  const int qt = blockIdx.x * 64, h = blockIdx.y, b = blockIdx.z;
  const int tid = threadIdx.x, lane = tid & 63, w = tid >> 6;
  const int l15 = lane & 15, l4 = lane >> 4;
  const int hoff = h * 64;

  s16x8 aq[2];
  {
    const u16* qp = Qg + (size_t)(b * SEQ + qt + w * 16 + l15) * D_MODEL + hoff + l4 * 8;
    aq[0] = *(const s16x8*)qp;
    aq[1] = *(const s16x8*)(qp + 32);
  }
  f32x4 oacc[4] = {};
  float mrow[4] = {-1e30f, -1e30f, -1e30f, -1e30f};
  float lrow[4] = {0.f, 0.f, 0.f, 0.f};

  const int nt = CAUSAL ? (qt >> 6) + 1 : SEQ / 64;
  for (int kt = 0; kt < nt; ++kt) {
    const int kv0 = kt * 64;
    #pragma unroll
    for (int i = 0; i < 2; ++i) {
      int t16 = i * 256 + tid;
      int r = t16 >> 3, sp = t16 & 7;
      int ss = (sp ^ (r & 7)) * 8;
      gload16(Kg + (size_t)(b * SEQ + kv0 + r) * D_MODEL + hoff + ss, &Ks[(i * 256 + w * 64) * 8]);
      gload16(Vt + ((size_t)(b * NHEAD + h) * 64 + r) * SEQ + kv0 + ss, &Vs[(i * 256 + w * 64) * 8]);
    }
    __syncthreads();

    f32x4 sac[4] = {};
    #pragma unroll
    for (int ks = 0; ks < 2; ++ks)
      #pragma unroll
      for (int jn = 0; jn < 4; ++jn) {
        int rr = jn * 16 + l15;
        s16x8 bk = *(const s16x8*)&Ks[(rr << 6) + (((ks * 4 + l4) ^ (rr & 7)) << 3)];
        sac[jn] = __builtin_amdgcn_mfma_f32_16x16x32_bf16(aq[ks], bk, sac[jn], 0, 0, 0);
      }

    int pok[4];
    #pragma unroll
    for (int jn = 0; jn < 4; ++jn)
      pok[jn] = (ktok[b * SEQ + kv0 + jn * 16 + l15] != PAD_ID) ? 1 : 0;

    float p[4][4], scl[4];
    #pragma unroll
    for (int r = 0; r < 4; ++r) {
      const int qg = qt + w * 16 + l4 * 4 + r;
      float sv[4];
      float mloc = -1e30f;
      #pragma unroll
      for (int jn = 0; jn < 4; ++jn) {
        int kvg = kv0 + jn * 16 + l15;
        float sc = sac[jn][r] * 0.125f;
        bool ok = (pok[jn] != 0) && (!CAUSAL || (kvg <= qg));
        sv[jn] = ok ? sc : -1e30f;
        mloc = fmaxf(mloc, sv[jn]);
      }
      #pragma unroll
      for (int o = 1; o < 16; o <<= 1) mloc = fmaxf(mloc, __shfl_xor(mloc, o, 16));
      float mn = fmaxf(mrow[r], mloc);
      scl[r] = __expf(mrow[r] - mn);
      mrow[r] = mn;
      float rs = 0.f;
      #pragma unroll
      for (int jn = 0; jn < 4; ++jn) {
        float pv = __expf(sv[jn] - mn);
        p[jn][r] = pv;
        rs += pv;
      }
      #pragma unroll
      for (int o = 1; o < 16; o <<= 1) rs += __shfl_xor(rs, o, 16);
      lrow[r] = lrow[r] * scl[r] + rs;
    }
    #pragma unroll
    for (int jn = 0; jn < 4; ++jn)
      #pragma unroll
      for (int r = 0; r < 4; ++r) oacc[jn][r] *= scl[r];

    // P -> LDS (wave-private, swizzled), then PV
    #pragma unroll
    for (int jn = 0; jn < 4; ++jn)
      #pragma unroll
      for (int r = 0; r < 4; ++r) {
        int prow = l4 * 4 + r, pcol = jn * 16 + l15;
        Ps[w * 1024 + ((prow * 64 + pcol) ^ ((prow & 7) << 3))] = f2bf(p[jn][r]);
      }
    #pragma unroll
    for (int ks = 0; ks < 2; ++ks) {
      s16x8 pa = *(const s16x8*)&Ps[w * 1024 + ((l15 * 64 + ks * 32 + l4 * 8) ^ ((l15 & 7) << 3))];
      #pragma unroll
      for (int jn = 0; jn < 4; ++jn) {
        int rr = jn * 16 + l15;
        s16x8 bv = *(const s16x8*)&Vs[(rr << 6) + (((ks * 4 + l4) ^ (rr & 7)) << 3)];
        oacc[jn] = __builtin_amdgcn_mfma_f32_16x16x32_bf16(pa, bv, oacc[jn], 0, 0, 0);
      }
    }
    __syncthreads();
  }

  float inv[4];
  #pragma unroll
  for (int r = 0; r < 4; ++r) inv[r] = 1.0f / lrow[r];
  #pragma unroll
  for (int jn = 0; jn < 4; ++jn)
    #pragma unroll
    for (int r = 0; r < 4; ++r)
      Og[(size_t)(b * SEQ + qt + w * 16 + l4 * 4 + r) * D_MODEL + hoff + jn * 16 + l15] =
          f2bf(oacc[jn][r] * inv[r]);
}

// ------------------------------------------------------------------ host
extern "C" void kernel_launch(void* const* d_in, const int* in_sizes, int n_in,
                              void* d_out, int out_size, void* d_ws, size_t ws_size,
                              hipStream_t stream)
{
  const int*   src        = (const int*)  d_in[0];
  const int*   tgt        = (const int*)  d_in[1];
  const float* src_emb    = (const float*)d_in[2];
  const float* tgt_emb    = (const float*)d_in[3];
  const float* pe         = (const float*)d_in[4];
  const float* enc_attn_w = (const float*)d_in[5];
  const float* enc_attn_b = (const float*)d_in[6];
  const float* enc_ff_w1  = (const float*)d_in[7];
  const float* enc_ff_b1  = (const float*)d_in[8];
  const float* enc_ff_w2  = (const float*)d_in[9];
  const float* enc_ff_b2  = (const float*)d_in[10];
  const float* enc_ln_g   = (const float*)d_in[11];
  const float* enc_ln_bb  = (const float*)d_in[12];
  const float* dec_self_w = (const float*)d_in[13];
  const float* dec_self_b = (const float*)d_in[14];
  const float* dec_src_w  = (const float*)d_in[15];
  const float* dec_src_b  = (const float*)d_in[16];
  const float* dec_ff_w1  = (const float*)d_in[17];
  const float* dec_ff_b1  = (const float*)d_in[18];
  const float* dec_ff_w2  = (const float*)d_in[19];
  const float* dec_ff_b2  = (const float*)d_in[20];
  const float* dec_ln_g   = (const float*)d_in[21];
  const float* dec_ln_bb  = (const float*)d_in[22];
  const float* fin_ln_g   = (const float*)d_in[23];
  const float* fin_ln_b   = (const float*)d_in[24];
  const float* fc_w       = (const float*)d_in[25];
  const float* fc_b       = (const float*)d_in[26];
  float* out = (float*)d_out;

  const size_t DD = (size_t)D_MODEL * D_MODEL;      // 262144
  const size_t FD = (size_t)D_MODEL * DFF_;         // 1048576
  const size_t TD = (size_t)NTOK * D_MODEL;         // 2097152

  // ---- scratch in d_out (all dead before the final GEMM writes d_out) ----
  char* ob = (char*)d_out;
  size_t off = 0;
  auto alloco = [&](size_t bytes) { void* p = ob + off; off += (bytes + 255) & ~(size_t)255; return p; };
  u16* wt_enc_attn = (u16*)alloco(24 * DD * 2);
  u16* wt_dec_self = (u16*)alloco(24 * DD * 2);
  u16* wt_dec_src  = (u16*)alloco(24 * DD * 2);
  u16* wt_enc_ff1  = (u16*)alloco(6 * FD * 2);
  u16* wt_enc_ff2  = (u16*)alloco(6 * FD * 2);
  u16* wt_dec_ff1  = (u16*)alloco(6 * FD * 2);
  u16* wt_dec_ff2  = (u16*)alloco(6 * FD * 2);
  u16* qb   = (u16*)alloco(3 * TD * 2);             // q,k,v contiguous (z-batched GEMM out)
  u16* kb   = qb + TD;
  u16* vb   = kb + TD;
  u16* vtb  = (u16*)alloco(TD * 2);
  u16* aob  = (u16*)alloco(TD * 2);
  u16* hbb  = (u16*)alloco((size_t)NTOK * DFF_ * 2);
  u16* memb = (u16*)alloco(TD * 2);

  // ---- mandatory ws (live during final GEMM): fc Wt, residuals, LN out ----
  char* wsb = (char*)d_ws;
  u16*   fcwt = (u16*)wsb;                                   // [32000][512] bf16
  size_t wo = ((size_t)VOCAB * D_MODEL * 2 + 255) & ~(size_t)255;
  float* xe  = (float*)(wsb + wo); wo += TD * 4;
  float* yd  = (float*)(wsb + wo); wo += TD * 4;
  u16*   x2b = (u16*)(wsb + wo);

  dim3 blk(256);
  dim3 gProj(4, 32, 1), gQKV(4, 32, 3), gKV(4, 32, 2);
  dim3 gFF1(16, 32, 1), gFC(250, 32, 1);
  dim3 gAttn(SEQ / 64, NHEAD, BATCH);
  dim3 gVT(SEQ / 64, 1, BATCH * NHEAD);
  const long long llDD = (long long)DD, llTD = (long long)TD;

  // ---- weight conversion (f32 [K][N] -> bf16 [N][K]) ----
  tconv_kernel<<<dim3(8, 8, 24), blk, 0, stream>>>(enc_attn_w, wt_enc_attn, 512, 512);
  tconv_kernel<<<dim3(8, 8, 24), blk, 0, stream>>>(dec_self_w, wt_dec_self, 512, 512);
  tconv_kernel<<<dim3(8, 8, 24), blk, 0, stream>>>(dec_src_w,  wt_dec_src,  512, 512);
  tconv_kernel<<<dim3(32, 8, 6), blk, 0, stream>>>(enc_ff_w1, wt_enc_ff1, 512, 2048);
  tconv_kernel<<<dim3(8, 32, 6), blk, 0, stream>>>(enc_ff_w2, wt_enc_ff2, 2048, 512);
  tconv_kernel<<<dim3(32, 8, 6), blk, 0, stream>>>(dec_ff_w1, wt_dec_ff1, 512, 2048);
  tconv_kernel<<<dim3(8, 32, 6), blk, 0, stream>>>(dec_ff_w2, wt_dec_ff2, 2048, 512);
  tconv_kernel<<<dim3(500, 8, 1), blk, 0, stream>>>(fc_w, fcwt, 512, VOCAB);

  // ---- encoder ----
  embed_kernel<<<dim3(2048), blk, 0, stream>>>(src, src_emb, pe, xe);
  for (int l = 0; l < NLAYER; ++l) {
    ln_kernel<<<dim3(NTOK), blk, 0, stream>>>(xe, enc_ln_g + (size_t)(l * 2 + 0) * D_MODEL,
                                              enc_ln_bb + (size_t)(l * 2 + 0) * D_MODEL, x2b);
    mm_kernel<2><<<gQKV, blk, 0, stream>>>(x2b, wt_enc_attn + (size_t)l * 4 * DD,
        enc_attn_b + (size_t)l * 4 * D_MODEL, nullptr, qb, NTOK, 512, 512, llDD, D_MODEL, llTD);
    vtrans_kernel<<<gVT, blk, 0, stream>>>(vb, vtb);
    fattn_kernel<0><<<gAttn, blk, 0, stream>>>(qb, kb, vtb, src, aob);
    mm_kernel<1><<<gProj, blk, 0, stream>>>(aob, wt_enc_attn + (size_t)(l * 4 + 3) * DD,
        enc_attn_b + (size_t)(l * 4 + 3) * D_MODEL, xe, xe, NTOK, 512, 512, 0, 0, 0);
    ln_kernel<<<dim3(NTOK), blk, 0, stream>>>(xe, enc_ln_g + (size_t)(l * 2 + 1) * D_MODEL,
                                              enc_ln_bb + (size_t)(l * 2 + 1) * D_MODEL, x2b);
    mm_kernel<3><<<gFF1, blk, 0, stream>>>(x2b, wt_enc_ff1 + (size_t)l * FD,
        enc_ff_b1 + (size_t)l * DFF_, nullptr, hbb, NTOK, DFF_, 512, 0, 0, 0);
    mm_kernel<1><<<gProj, blk, 0, stream>>>(hbb, wt_enc_ff2 + (size_t)l * FD,
        enc_ff_b2 + (size_t)l * D_MODEL, xe, xe, NTOK, 512, DFF_, 0, 0, 0);
  }
  cvtbf_kernel<<<dim3(1024), blk, 0, stream>>>(xe, memb, NTOK * D_MODEL);

  // ---- decoder ----
  embed_kernel<<<dim3(2048), blk, 0, stream>>>(tgt, tgt_emb, pe, yd);
  for (int l = 0; l < NLAYER; ++l) {
    const u16* Ws = wt_dec_self + (size_t)l * 4 * DD;
    const u16* Wc = wt_dec_src + (size_t)l * 4 * DD;
    const float* bs  = dec_self_b + (size_t)l * 4 * D_MODEL;
    const float* bcb = dec_src_b + (size_t)l * 4 * D_MODEL;
    // self-attention (causal)
    ln_kernel<<<dim3(NTOK), blk, 0, stream>>>(yd, dec_ln_g + (size_t)(l * 3 + 0) * D_MODEL,
                                              dec_ln_bb + (size_t)(l * 3 + 0) * D_MODEL, x2b);
    mm_kernel<2><<<gQKV, blk, 0, stream>>>(x2b, Ws, bs, nullptr, qb, NTOK, 512, 512, llDD, D_MODEL, llTD);
    vtrans_kernel<<<gVT, blk, 0, stream>>>(vb, vtb);
    fattn_kernel<1><<<gAttn, blk, 0, stream>>>(qb, kb, vtb, tgt, aob);
    mm_kernel<1><<<gProj, blk, 0, stream>>>(aob, Ws + 3 * DD, bs + 3 * D_MODEL, yd, yd,
                                            NTOK, 512, 512, 0, 0, 0);
    // cross-attention
    ln_kernel<<<dim3(NTOK), blk, 0, stream>>>(yd, dec_ln_g + (size_t)(l * 3 + 1) * D_MODEL,
                                              dec_ln_bb + (size_t)(l * 3 + 1) * D_MODEL, x2b);
    mm_kernel<2><<<gProj, blk, 0, stream>>>(x2b, Wc, bcb, nullptr, qb, NTOK, 512, 512, 0, 0, 0);
    mm_kernel<2><<<gKV, blk, 0, stream>>>(memb, Wc + DD, bcb + D_MODEL, nullptr, kb,
                                          NTOK, 512, 512, llDD, D_MODEL, llTD);
    vtrans_kernel<<<gVT, blk, 0, stream>>>(vb, vtb);
    fattn_kernel<0><<<gAttn, blk, 0, stream>>>(qb, kb, vtb, src, aob);
    mm_kernel<1><<<gProj, blk, 0, stream>>>(aob, Wc + 3 * DD, bcb + 3 * D_MODEL, yd, yd,
                                            NTOK, 512, 512, 0, 0, 0);
    // feed-forward
    ln_kernel<<<dim3(NTOK), blk, 0, stream>>>(yd, dec_ln_g + (size_t)(l * 3 + 2) * D_MODEL,
                                              dec_ln_bb + (size_t)(l * 3 + 2) * D_MODEL, x2b);
    mm_kernel<3><<<gFF1, blk, 0, stream>>>(x2b, wt_dec_ff1 + (size_t)l * FD,
        dec_ff_b1 + (size_t)l * DFF_, nullptr, hbb, NTOK, DFF_, 512, 0, 0, 0);
    mm_kernel<1><<<gProj, blk, 0, stream>>>(hbb, wt_dec_ff2 + (size_t)l * FD,
        dec_ff_b2 + (size_t)l * D_MODEL, yd, yd, NTOK, 512, DFF_, 0, 0, 0);
  }

  // ---- head ----
  ln_kernel<<<dim3(NTOK), blk, 0, stream>>>(yd, fin_ln_g, fin_ln_b, x2b);
  mm_kernel<0><<<gFC, blk, 0, stream>>>(x2b, fcwt, fc_b, nullptr, out, NTOK, VOCAB, 512, 0, 0, 0);

  (void)in_sizes; (void)n_in; (void)out_size; (void)ws_size;
}

// Round 3
// 2690.020 us; speedup vs baseline: 4.8334x; 1.3561x over previous
//
#include <hip/hip_runtime.h>
#include <math.h>

#define D_MODEL 512
#define NHEAD   8
#define NLAYER  6
#define DFF_    2048
#define VOCAB   32000
#define BATCH   2
#define SEQ     2048
#define NTOK    (BATCH*SEQ)
#define PAD_ID  1

typedef __attribute__((ext_vector_type(8))) short s16x8;
typedef __attribute__((ext_vector_type(4))) float f32x4;
typedef unsigned short u16;
typedef unsigned int   u32;
typedef unsigned long long u64;

__device__ __forceinline__ u16 f2bf(float x) {
  u32 u = __builtin_bit_cast(u32, x);
  u += 0x7FFFu + ((u >> 16) & 1u);
  return (u16)(u >> 16);
}

__device__ __forceinline__ float exp2i(float x) {
  float r; asm("v_exp_f32 %0, %1" : "=v"(r) : "v"(x)); return r;
}

__device__ __forceinline__ void gload16(const void* g, void* l) {
  __builtin_amdgcn_global_load_lds(
      (const __attribute__((address_space(1))) u32*)g,
      (__attribute__((address_space(3))) u32*)l, 16, 0, 0);
}

#define CEXP 0.1803368802f   /* 0.125 * log2(e) */

// ------------------------------------------------------------------ embed (f32 residual stream)
__global__ __launch_bounds__(256) void embed_kernel(
    const int* __restrict__ tok, const float* __restrict__ emb,
    const float* __restrict__ pe, float* __restrict__ out)
{
  const int total = NTOK * D_MODEL;
  for (int i = blockIdx.x * 256 + threadIdx.x; i < total; i += gridDim.x * 256) {
    int t = i >> 9;
    int d = i & 511;
    int s = t & (SEQ - 1);
    out[i] = emb[(size_t)tok[t] * D_MODEL + d] + pe[(size_t)s * D_MODEL + d];
  }
}

// ------------------------------------------------------------------ pad mask: one u64 per 64 tokens
__global__ __launch_bounds__(64) void padmask_kernel(
    const int* __restrict__ tok, u64* __restrict__ pm)
{
  int b = blockIdx.y, t = blockIdx.x;
  int lane = threadIdx.x;
  u64 m = __ballot(tok[(size_t)b * SEQ + t * 64 + lane] != PAD_ID);
  if (lane == 0) pm[b * (SEQ / 64) + t] = m;
}

// ------------------------------------------------------------------ layernorm: f32 in -> bf16 out
__global__ __launch_bounds__(256) void ln_kernel(
    const float* __restrict__ x, const float* __restrict__ g,
    const float* __restrict__ bb, u16* __restrict__ y)
{
  __shared__ float red[8];
  const size_t row = blockIdx.x;
  const float* xr = x + row * D_MODEL;
  u16* yr = y + row * D_MODEL;
  const int t = threadIdx.x;
  float a0 = xr[t], a1 = xr[t + 256];
  float s = a0 + a1;
  #pragma unroll
  for (int o = 32; o > 0; o >>= 1) s += __shfl_down(s, o, 64);
  int wv = t >> 6, ln = t & 63;
  if (ln == 0) red[wv] = s;
  __syncthreads();
  if (t == 0) red[4] = red[0] + red[1] + red[2] + red[3];
  __syncthreads();
  float mean = red[4] * (1.0f / D_MODEL);
  float d0 = a0 - mean, d1 = a1 - mean;
  float vs = d0 * d0 + d1 * d1;
  #pragma unroll
  for (int o = 32; o > 0; o >>= 1) vs += __shfl_down(vs, o, 64);
  if (ln == 0) red[wv] = vs;
  __syncthreads();
  if (t == 0) red[5] = red[0] + red[1] + red[2] + red[3];
  __syncthreads();
  float inv = rsqrtf(red[5] * (1.0f / D_MODEL) + 1e-5f);
  yr[t]       = f2bf(d0 * inv * g[t]       + bb[t]);
  yr[t + 256] = f2bf(d1 * inv * g[t + 256] + bb[t + 256]);
}

// ------------------------------------------------------------------ f32 -> bf16 elementwise
__global__ __launch_bounds__(256) void cvtbf_kernel(
    const float* __restrict__ s, u16* __restrict__ d, int n)
{
  int i = (blockIdx.x * 256 + threadIdx.x) * 8;
  if (i >= n) return;
  float4 a = *(const float4*)&s[i];
  float4 b = *(const float4*)&s[i + 4];
  u32 p0 = (u32)f2bf(a.x) | ((u32)f2bf(a.y) << 16);
  u32 p1 = (u32)f2bf(a.z) | ((u32)f2bf(a.w) << 16);
  u32 p2 = (u32)f2bf(b.x) | ((u32)f2bf(b.y) << 16);
  u32 p3 = (u32)f2bf(b.z) | ((u32)f2bf(b.w) << 16);
  uint4 o; o.x = p0; o.y = p1; o.z = p2; o.w = p3;
  *(uint4*)&d[i] = o;
}

// ------------------------------------------------------------------ transpose+convert: src f32 [K][N] -> dst bf16 [N][K]
__global__ __launch_bounds__(256) void tconv_kernel(
    const float* __restrict__ src, u16* __restrict__ dst, int K, int N)
{
  __shared__ float tile[64][65];
  const size_t z = blockIdx.z;
  src += z * (size_t)K * N;
  dst += z * (size_t)K * N;
  const int n0 = blockIdx.x * 64, k0 = blockIdx.y * 64;
  const int t = threadIdx.x;
  const int cr = t >> 4, cc = (t & 15) * 4;
  #pragma unroll
  for (int it = 0; it < 4; ++it) {
    int kr = cr + it * 16;
    float4 v = *(const float4*)&src[(size_t)(k0 + kr) * N + n0 + cc];
    tile[kr][cc] = v.x; tile[kr][cc + 1] = v.y; tile[kr][cc + 2] = v.z; tile[kr][cc + 3] = v.w;
  }
  __syncthreads();
  #pragma unroll
  for (int it = 0; it < 4; ++it) {
    int nr = cr + it * 16;
    u32 lo = (u32)f2bf(tile[cc + 0][nr]) | ((u32)f2bf(tile[cc + 1][nr]) << 16);
    u32 hi = (u32)f2bf(tile[cc + 2][nr]) | ((u32)f2bf(tile[cc + 3][nr]) << 16);
    uint2 pk; pk.x = lo; pk.y = hi;
    *(uint2*)&dst[(size_t)(n0 + nr) * K + k0 + cc] = pk;
  }
}

// ------------------------------------------------------------------ V transpose: v [NTOK][512] bf16 -> vt [B*H][64][SEQ]
__global__ __launch_bounds__(256) void vtrans_kernel(
    const u16* __restrict__ v, u16* __restrict__ vt)
{
  __shared__ u16 tile[64][65];
  const int bh = blockIdx.z, s0 = blockIdx.x * 64;
  const int b = bh >> 3, h = bh & 7;
  const int t = threadIdx.x;
  const int lr = t >> 3, lc = (t & 7) * 8;
  #pragma unroll
  for (int it = 0; it < 2; ++it) {
    int srow = lr + it * 32;
    s16x8 val = *(const s16x8*)(v + (size_t)(b * SEQ + s0 + srow) * D_MODEL + h * 64 + lc);
    #pragma unroll
    for (int j = 0; j < 8; ++j) tile[srow][lc + j] = (u16)val[j];
  }
  __syncthreads();
  #pragma unroll
  for (int it = 0; it < 2; ++it) {
    int drow = lr + it * 32;
    s16x8 o;
    #pragma unroll
    for (int j = 0; j < 8; ++j) o[j] = (short)tile[lc + j][drow];
    *(s16x8*)(vt + ((size_t)bh * 64 + drow) * SEQ + s0 + lc) = o;
  }
}

// ------------------------------------------------------------------ bf16 MFMA GEMM: C[M,N] = A[M,K] @ Wt[N,K]^T + bias
// MODE 0: f32 out, 1: f32 out + res, 2: bf16 out, 3: bf16 out + relu
// BM x 128 tile, BK=64, 4 waves (2x2). XOR-swizzled LDS.
template<int MODE, int BM>
__global__ __launch_bounds__(256, 2) void mm_kernel(
    const u16* __restrict__ A, const u16* __restrict__ Wt,
    const float* __restrict__ bias, const float* __restrict__ res,
    void* __restrict__ Cout, int M, int N, int K,
    long long wStride, long long bStride, long long cStride)
{
  constexpr int MI = BM / 32;           // fragments per wave in M
  __shared__ u16 As[BM * 64];
  __shared__ u16 Bs[128 * 64];
  const int z = blockIdx.z;
  Wt   += (size_t)z * wStride;
  bias += (size_t)z * bStride;
  const int bm = blockIdx.y * BM, bn = blockIdx.x * 128;
  const int tid = threadIdx.x, lane = tid & 63, w = tid >> 6;
  const int wm = w >> 1, wn = w & 1;
  const int l15 = lane & 15, l4 = lane >> 4;
  const int wrow0 = wm * (BM / 2);
  const u16* aBase = A  + (size_t)bm * K;
  const u16* bBase = Wt + (size_t)bn * K;
  f32x4 acc[MI][4] = {};

  for (int k0 = 0; k0 < K; k0 += 64) {
    #pragma unroll
    for (int i = 0; i < BM / 32; ++i) {
      int lin = i * 256 + tid;
      int r = lin >> 3, sp = lin & 7;
      gload16(aBase + (size_t)r * K + k0 + ((sp ^ (r & 7)) * 8), &As[(i * 256 + w * 64) * 8]);
    }
    #pragma unroll
    for (int i = 0; i < 4; ++i) {
      int lin = i * 256 + tid;
      int r = lin >> 3, sp = lin & 7;
      gload16(bBase + (size_t)r * K + k0 + ((sp ^ (r & 7)) * 8), &Bs[(i * 256 + w * 64) * 8]);
    }
    __syncthreads();
    #pragma unroll
    for (int ks = 0; ks < 2; ++ks) {
      s16x8 af[MI], bf[4];
      #pragma unroll
      for (int mi = 0; mi < MI; ++mi) {
        int rr = wrow0 + mi * 16 + l15;
        af[mi] = *(const s16x8*)&As[(rr << 6) + (((ks * 4 + l4) ^ (rr & 7)) << 3)];
      }
      #pragma unroll
      for (int ni = 0; ni < 4; ++ni) {
        int rr = wn * 64 + ni * 16 + l15;
        bf[ni] = *(const s16x8*)&Bs[(rr << 6) + (((ks * 4 + l4) ^ (rr & 7)) << 3)];
      }
      #pragma unroll
      for (int mi = 0; mi < MI; ++mi)
        #pragma unroll
        for (int ni = 0; ni < 4; ++ni)
          acc[mi][ni] = __builtin_amdgcn_mfma_f32_16x16x32_bf16(af[mi], bf[ni], acc[mi][ni], 0, 0, 0);
    }
    __syncthreads();
  }

  #pragma unroll
  for (int ni = 0; ni < 4; ++ni) {
    int col = bn + wn * 64 + ni * 16 + l15;
    float bb = bias[col];
    #pragma unroll
    for (int mi = 0; mi < MI; ++mi) {
      #pragma unroll
      for (int r = 0; r < 4; ++r) {
        int row = bm + wrow0 + mi * 16 + l4 * 4 + r;
        size_t off = (size_t)z * cStride + (size_t)row * N + col;
        float v = acc[mi][ni][r] + bb;
        if (MODE == 1) v += res[(size_t)row * N + col];
        if (MODE == 3) v = fmaxf(v, 0.0f);
        if (MODE <= 1) ((float*)Cout)[off] = v;
        else           ((u16*)Cout)[off] = f2bf(v);
      }
    }
  }
}

// ------------------------------------------------------------------ flash attention, bf16 MFMA, KVBLK=128, dbuf prefetch
// grid (SEQ/64, H, B), 4 waves; wave w owns q-rows [qt+16w, qt+16w+16)
template<int CAUSAL>
__global__ __launch_bounds__(256, 2) void fattn_kernel(
    const u16* __restrict__ Qg, const u16* __restrict__ Kg,
    const u16* __restrict__ Vt, const u64* __restrict__ padm,
    u16* __restrict__ Og)
{
  __shared__ u16 Ks[2][128 * 64];   // [kv][d], XOR-swizzled (8-groups)
  __shared__ u16 Vs[2][64 * 128];   // [d][kv], XOR-swizzled (16-groups)
  __shared__ u16 Ps[4][16 * 128];   // per-wave P, XOR-swizzled (16-groups)
  const int qtile = CAUSAL ? (int)(gridDim.x - 1 - blockIdx.x) : (int)blockIdx.x;
  const int qt = qtile * 64;
  const int h = blockIdx.y, b = blockIdx.z;
  const int tid = threadIdx.x, lane = tid & 63, w = tid >> 6;
  const int l15 = lane & 15, l4 = lane >> 4;
  const int hoff = h * 64;
  const u16* Kbase = Kg + (size_t)(b * SEQ) * D_MODEL + hoff;
  const u16* Vbase = Vt + (size_t)(b * NHEAD + h) * 64 * SEQ;
  const u64* pmb = padm + b * (SEQ / 64);

  s16x8 aq[2];
  {
    const u16* qp = Qg + (size_t)(b * SEQ + qt + w * 16 + l15) * D_MODEL + hoff + l4 * 8;
    aq[0] = *(const s16x8*)qp;
    aq[1] = *(const s16x8*)(qp + 32);
  }

  f32x4 oacc[4] = {};
  float mrow[4] = {-1e30f, -1e30f, -1e30f, -1e30f};
  float lrow[4] = {0.f, 0.f, 0.f, 0.f};
  const int nt = CAUSAL ? (qt >> 7) + 1 : SEQ / 128;

  #define STAGE(KV0, BUF)                                                              \
    {                                                                                  \
      _Pragma("unroll")                                                                \
      for (int it = 0; it < 4; ++it) {                                                 \
        int lin = it * 256 + tid;                                                      \
        int rr = lin >> 3, sp = lin & 7;                                               \
        gload16(Kbase + (size_t)((KV0) + rr) * D_MODEL + ((sp ^ (rr & 7)) * 8),        \
                &Ks[BUF][(it * 256 + w * 64) * 8]);                                    \
      }                                                                                \
      _Pragma("unroll")                                                                \
      for (int it = 0; it < 4; ++it) {                                                 \
        int lin = it * 256 + tid;                                                      \
        int rr = lin >> 4, ko = lin & 15;                                              \
        gload16(Vbase + (size_t)rr * SEQ + (KV0) + ((ko ^ (rr & 15)) * 8),             \
                &Vs[BUF][(it * 256 + w * 64) * 8]);                                    \
      }                                                                                \
    }

  STAGE(0, 0);
  __syncthreads();

  for (int kt = 0; kt < nt; ++kt) {
    const int kv0 = kt * 128;
    const int cur = kt & 1;
    if (kt + 1 < nt) STAGE(kv0 + 128, cur ^ 1);

    // S = Q K^T (raw scale; 1/8 folded into exp constant)
    f32x4 sac[8] = {};
    #pragma unroll
    for (int ks = 0; ks < 2; ++ks)
      #pragma unroll
      for (int jn = 0; jn < 8; ++jn) {
        int rr = jn * 16 + l15;
        s16x8 bk = *(const s16x8*)&Ks[cur][(rr << 6) + (((ks * 4 + l4) ^ (rr & 7)) << 3)];
        sac[jn] = __builtin_amdgcn_mfma_f32_16x16x32_bf16(aq[ks], bk, sac[jn], 0, 0, 0);
      }

    const u64 m0 = pmb[(kv0 >> 6)];
    const u64 m1 = pmb[(kv0 >> 6) + 1];
    const bool lastC = CAUSAL && (kt == nt - 1);
    if (((m0 & m1) != ~0ull) || lastC) {
      #pragma unroll
      for (int jn = 0; jn < 8; ++jn) {
        int kvg = kv0 + jn * 16 + l15;
        u64 mm = (jn < 4) ? m0 : m1;
        bool okp = (mm >> ((jn & 3) * 16 + l15)) & 1;
        #pragma unroll
        for (int r = 0; r < 4; ++r) {
          int qg = qt + w * 16 + l4 * 4 + r;
          bool ok = okp && (!CAUSAL || kvg <= qg);
          if (!ok) sac[jn][r] = -1e30f;
        }
      }
    }

    // row max (defer-max: only rescale when growth > 64 raw = 8 scaled)
    float mx[4];
    #pragma unroll
    for (int r = 0; r < 4; ++r) {
      float m = fmaxf(fmaxf(fmaxf(sac[0][r], sac[1][r]), fmaxf(sac[2][r], sac[3][r])),
                      fmaxf(fmaxf(sac[4][r], sac[5][r]), fmaxf(sac[6][r], sac[7][r])));
      #pragma unroll
      for (int o = 1; o < 16; o <<= 1) m = fmaxf(m, __shfl_xor(m, o, 16));
      mx[r] = m;
    }
    float growth = fmaxf(fmaxf(mx[0] - mrow[0], mx[1] - mrow[1]),
                         fmaxf(mx[2] - mrow[2], mx[3] - mrow[3]));
    if (__any(growth > 64.0f)) {
      #pragma unroll
      for (int r = 0; r < 4; ++r) {
        float mn = fmaxf(mrow[r], mx[r]);
        float sc = exp2i((mrow[r] - mn) * CEXP);
        mrow[r] = mn;
        lrow[r] *= sc;
        #pragma unroll
        for (int jn = 0; jn < 4; ++jn) oacc[jn][r] *= sc;
      }
    }

    // P = exp, write to per-wave LDS, accumulate row sums
    #pragma unroll
    for (int r = 0; r < 4; ++r) {
      const int prow = l4 * 4 + r;
      float rs = 0.f;
      #pragma unroll
      for (int jn = 0; jn < 8; ++jn) {
        float pv = exp2i((sac[jn][r] - mrow[r]) * CEXP);
        rs += pv;
        int g = ((jn * 2 + (l15 >> 3)) ^ prow) & 15;
        Ps[w][prow * 128 + g * 8 + (l15 & 7)] = f2bf(pv);
      }
      #pragma unroll
      for (int o = 1; o < 16; o <<= 1) rs += __shfl_xor(rs, o, 16);
      lrow[r] += rs;
    }

    // O += P @ V
    #pragma unroll
    for (int kslot = 0; kslot < 4; ++kslot) {
      s16x8 pa = *(const s16x8*)&Ps[w][l15 * 128 + ((((kslot * 4 + l4) ^ l15) & 15) << 3)];
      #pragma unroll
      for (int jn = 0; jn < 4; ++jn) {
        int rr = jn * 16 + l15;
        s16x8 bv = *(const s16x8*)&Vs[cur][(rr << 7) + (((kslot * 4 + l4) ^ (rr & 15)) << 3)];
        oacc[jn] = __builtin_amdgcn_mfma_f32_16x16x32_bf16(pa, bv, oacc[jn], 0, 0, 0);
      }
    }
    __syncthreads();
  }
  #undef STAGE

  float inv[4];
  #pragma unroll
  for (int r = 0; r < 4; ++r) inv[r] = 1.0f / lrow[r];
  #pragma unroll
  for (int jn = 0; jn < 4; ++jn)
    #pragma unroll
    for (int r = 0; r < 4; ++r)
      Og[(size_t)(b * SEQ + qt + w * 16 + l4 * 4 + r) * D_MODEL + hoff + jn * 16 + l15] =
          f2bf(oacc[jn][r] * inv[r]);
}

// ------------------------------------------------------------------ host
extern "C" void kernel_launch(void* const* d_in, const int* in_sizes, int n_in,
                              void* d_out, int out_size, void* d_ws, size_t ws_size,
                              hipStream_t stream)
{
  const int*   src        = (const int*)  d_in[0];
  const int*   tgt        = (const int*)  d_in[1];
  const float* src_emb    = (const float*)d_in[2];
  const float* tgt_emb    = (const float*)d_in[3];
  const float* pe         = (const float*)d_in[4];
  const float* enc_attn_w = (const float*)d_in[5];
  const float* enc_attn_b = (const float*)d_in[6];
  const float* enc_ff_w1  = (const float*)d_in[7];
  const float* enc_ff_b1  = (const float*)d_in[8];
  const float* enc_ff_w2  = (const float*)d_in[9];
  const float* enc_ff_b2  = (const float*)d_in[10];
  const float* enc_ln_g   = (const float*)d_in[11];
  const float* enc_ln_bb  = (const float*)d_in[12];
  const float* dec_self_w = (const float*)d_in[13];
  const float* dec_self_b = (const float*)d_in[14];
  const float* dec_src_w  = (const float*)d_in[15];
  const float* dec_src_b  = (const float*)d_in[16];
  const float* dec_ff_w1  = (const float*)d_in[17];
  const float* dec_ff_b1  = (const float*)d_in[18];
  const float* dec_ff_w2  = (const float*)d_in[19];
  const float* dec_ff_b2  = (const float*)d_in[20];
  const float* dec_ln_g   = (const float*)d_in[21];
  const float* dec_ln_bb  = (const float*)d_in[22];
  const float* fin_ln_g   = (const float*)d_in[23];
  const float* fin_ln_b   = (const float*)d_in[24];
  const float* fc_w       = (const float*)d_in[25];
  const float* fc_b       = (const float*)d_in[26];
  float* out = (float*)d_out;

  const size_t DD = (size_t)D_MODEL * D_MODEL;
  const size_t FD = (size_t)D_MODEL * DFF_;
  const size_t TD = (size_t)NTOK * D_MODEL;

  // ---- scratch in d_out (all dead before the final GEMM writes d_out) ----
  char* ob = (char*)d_out;
  size_t off = 0;
  auto alloco = [&](size_t bytes) { void* p = ob + off; off += (bytes + 255) & ~(size_t)255; return p; };
  u16* wt_enc_attn = (u16*)alloco(24 * DD * 2);
  u16* wt_dec_self = (u16*)alloco(24 * DD * 2);
  u16* wt_dec_src  = (u16*)alloco(24 * DD * 2);
  u16* wt_enc_ff1  = (u16*)alloco(6 * FD * 2);
  u16* wt_enc_ff2  = (u16*)alloco(6 * FD * 2);
  u16* wt_dec_ff1  = (u16*)alloco(6 * FD * 2);
  u16* wt_dec_ff2  = (u16*)alloco(6 * FD * 2);
  u16* qb   = (u16*)alloco(3 * TD * 2);
  u16* kb   = qb + TD;
  u16* vb   = kb + TD;
  u16* vtb  = (u16*)alloco(TD * 2);
  u16* aob  = (u16*)alloco(TD * 2);
  u16* hbb  = (u16*)alloco((size_t)NTOK * DFF_ * 2);
  u16* memb = (u16*)alloco(TD * 2);

  // ---- mandatory ws (live during final GEMM) ----
  char* wsb = (char*)d_ws;
  u16*   fcwt = (u16*)wsb;
  size_t wo = ((size_t)VOCAB * D_MODEL * 2 + 255) & ~(size_t)255;
  float* xe  = (float*)(wsb + wo); wo += TD * 4;
  float* yd  = (float*)(wsb + wo); wo += TD * 4;
  u16*   x2b = (u16*)(wsb + wo);   wo += TD * 2;
  u64*   pmS = (u64*)(wsb + wo);   wo += 1024;
  u64*   pmT = (u64*)(wsb + wo);

  dim3 blk(256);
  dim3 gP64(4, 64, 1), gQKV(4, 64, 3), gKV(4, 64, 2);
  dim3 gFF1(16, 32, 1), gFF2(4, 64, 1), gFC(250, 32, 1);
  dim3 gAttn(SEQ / 64, NHEAD, BATCH);
  dim3 gVT(SEQ / 64, 1, BATCH * NHEAD);
  dim3 gPM(SEQ / 64, BATCH);
  const long long llDD = (long long)DD, llTD = (long long)TD;

  // ---- one-time prep ----
  padmask_kernel<<<gPM, dim3(64), 0, stream>>>(src, pmS);
  padmask_kernel<<<gPM, dim3(64), 0, stream>>>(tgt, pmT);
  tconv_kernel<<<dim3(8, 8, 24), blk, 0, stream>>>(enc_attn_w, wt_enc_attn, 512, 512);
  tconv_kernel<<<dim3(8, 8, 24), blk, 0, stream>>>(dec_self_w, wt_dec_self, 512, 512);
  tconv_kernel<<<dim3(8, 8, 24), blk, 0, stream>>>(dec_src_w,  wt_dec_src,  512, 512);
  tconv_kernel<<<dim3(32, 8, 6), blk, 0, stream>>>(enc_ff_w1, wt_enc_ff1, 512, 2048);
  tconv_kernel<<<dim3(8, 32, 6), blk, 0, stream>>>(enc_ff_w2, wt_enc_ff2, 2048, 512);
  tconv_kernel<<<dim3(32, 8, 6), blk, 0, stream>>>(dec_ff_w1, wt_dec_ff1, 512, 2048);
  tconv_kernel<<<dim3(8, 32, 6), blk, 0, stream>>>(dec_ff_w2, wt_dec_ff2, 2048, 512);
  tconv_kernel<<<dim3(500, 8, 1), blk, 0, stream>>>(fc_w, fcwt, 512, VOCAB);

  // ---- encoder ----
  embed_kernel<<<dim3(2048), blk, 0, stream>>>(src, src_emb, pe, xe);
  for (int l = 0; l < NLAYER; ++l) {
    ln_kernel<<<dim3(NTOK), blk, 0, stream>>>(xe, enc_ln_g + (size_t)(l * 2 + 0) * D_MODEL,
                                              enc_ln_bb + (size_t)(l * 2 + 0) * D_MODEL, x2b);
    mm_kernel<2, 64><<<gQKV, blk, 0, stream>>>(x2b, wt_enc_attn + (size_t)l * 4 * DD,
        enc_attn_b + (size_t)l * 4 * D_MODEL, nullptr, qb, NTOK, 512, 512, llDD, D_MODEL, llTD);
    vtrans_kernel<<<gVT, blk, 0, stream>>>(vb, vtb);
    fattn_kernel<0><<<gAttn, blk, 0, stream>>>(qb, kb, vtb, pmS, aob);
    mm_kernel<1, 64><<<gP64, blk, 0, stream>>>(aob, wt_enc_attn + (size_t)(l * 4 + 3) * DD,
        enc_attn_b + (size_t)(l * 4 + 3) * D_MODEL, xe, xe, NTOK, 512, 512, 0, 0, 0);
    ln_kernel<<<dim3(NTOK), blk, 0, stream>>>(xe, enc_ln_g + (size_t)(l * 2 + 1) * D_MODEL,
                                              enc_ln_bb + (size_t)(l * 2 + 1) * D_MODEL, x2b);
    mm_kernel<3, 128><<<gFF1, blk, 0, stream>>>(x2b, wt_enc_ff1 + (size_t)l * FD,
        enc_ff_b1 + (size_t)l * DFF_, nullptr, hbb, NTOK, DFF_, 512, 0, 0, 0);
    mm_kernel<1, 64><<<gFF2, blk, 0, stream>>>(hbb, wt_enc_ff2 + (size_t)l * FD,
        enc_ff_b2 + (size_t)l * D_MODEL, xe, xe, NTOK, 512, DFF_, 0, 0, 0);
  }
  cvtbf_kernel<<<dim3(1024), blk, 0, stream>>>(xe, memb, NTOK * D_MODEL);

  // ---- decoder ----
  embed_kernel<<<dim3(2048), blk, 0, stream>>>(tgt, tgt_emb, pe, yd);
  for (int l = 0; l < NLAYER; ++l) {
    const u16* Ws = wt_dec_self + (size_t)l * 4 * DD;
    const u16* Wc = wt_dec_src + (size_t)l * 4 * DD;
    const float* bs  = dec_self_b + (size_t)l * 4 * D_MODEL;
    const float* bcb = dec_src_b + (size_t)l * 4 * D_MODEL;
    // self-attention (causal + tgt pad mask)
    ln_kernel<<<dim3(NTOK), blk, 0, stream>>>(yd, dec_ln_g + (size_t)(l * 3 + 0) * D_MODEL,
                                              dec_ln_bb + (size_t)(l * 3 + 0) * D_MODEL, x2b);
    mm_kernel<2, 64><<<gQKV, blk, 0, stream>>>(x2b, Ws, bs, nullptr, qb, NTOK, 512, 512, llDD, D_MODEL, llTD);
    vtrans_kernel<<<gVT, blk, 0, stream>>>(vb, vtb);
    fattn_kernel<1><<<gAttn, blk, 0, stream>>>(qb, kb, vtb, pmT, aob);
    mm_kernel<1, 64><<<gP64, blk, 0, stream>>>(aob, Ws + 3 * DD, bs + 3 * D_MODEL, yd, yd,
                                               NTOK, 512, 512, 0, 0, 0);
    // cross-attention (src pad mask)
    ln_kernel<<<dim3(NTOK), blk, 0, stream>>>(yd, dec_ln_g + (size_t)(l * 3 + 1) * D_MODEL,
                                              dec_ln_bb + (size_t)(l * 3 + 1) * D_MODEL, x2b);
    mm_kernel<2, 64><<<gP64, blk, 0, stream>>>(x2b, Wc, bcb, nullptr, qb, NTOK, 512, 512, 0, 0, 0);
    mm_kernel<2, 64><<<gKV, blk, 0, stream>>>(memb, Wc + DD, bcb + D_MODEL, nullptr, kb,
                                              NTOK, 512, 512, llDD, D_MODEL, llTD);
    vtrans_kernel<<<gVT, blk, 0, stream>>>(vb, vtb);
    fattn_kernel<0><<<gAttn, blk, 0, stream>>>(qb, kb, vtb, pmS, aob);
    mm_kernel<1, 64><<<gP64, blk, 0, stream>>>(aob, Wc + 3 * DD, bcb + 3 * D_MODEL, yd, yd,
                                               NTOK, 512, 512, 0, 0, 0);
    // feed-forward
    ln_kernel<<<dim3(NTOK), blk, 0, stream>>>(yd, dec_ln_g + (size_t)(l * 3 + 2) * D_MODEL,
                                              dec_ln_bb + (size_t)(l * 3 + 2) * D_MODEL, x2b);
    mm_kernel<3, 128><<<gFF1, blk, 0, stream>>>(x2b, wt_dec_ff1 + (size_t)l * FD,
        dec_ff_b1 + (size_t)l * DFF_, nullptr, hbb, NTOK, DFF_, 512, 0, 0, 0);
    mm_kernel<1, 64><<<gFF2, blk, 0, stream>>>(hbb, wt_dec_ff2 + (size_t)l * FD,
        dec_ff_b2 + (size_t)l * D_MODEL, yd, yd, NTOK, 512, DFF_, 0, 0, 0);
  }

  // ---- head ----
  ln_kernel<<<dim3(NTOK), blk, 0, stream>>>(yd, fin_ln_g, fin_ln_b, x2b);
  mm_kernel<0, 128><<<gFC, blk, 0, stream>>>(x2b, fcwt, fc_b, nullptr, out, NTOK, VOCAB, 512, 0, 0, 0);

  (void)in_sizes; (void)n_in; (void)out_size; (void)ws_size;
}

// Round 4
// 2515.978 us; speedup vs baseline: 5.1678x; 1.0692x over previous
//
#include <hip/hip_runtime.h>
#include <math.h>

#define D_MODEL 512
#define NHEAD   8
#define NLAYER  6
#define DFF_    2048
#define VOCAB   32000
#define BATCH   2
#define SEQ     2048
#define NTOK    (BATCH*SEQ)
#define PAD_ID  1

typedef __attribute__((ext_vector_type(8))) short s16x8;
typedef __attribute__((ext_vector_type(4))) float f32x4;
typedef unsigned short u16;
typedef unsigned int   u32;
typedef unsigned long long u64;

__device__ __forceinline__ u16 f2bf(float x) {
  u32 u = __builtin_bit_cast(u32, x);
  u += 0x7FFFu + ((u >> 16) & 1u);
  return (u16)(u >> 16);
}

__device__ __forceinline__ float exp2i(float x) {
  float r; asm("v_exp_f32 %0, %1" : "=v"(r) : "v"(x)); return r;
}

__device__ __forceinline__ void gload16(const void* g, void* l) {
  __builtin_amdgcn_global_load_lds(
      (const __attribute__((address_space(1))) u32*)g,
      (__attribute__((address_space(3))) u32*)l, 16, 0, 0);
}

#define CEXP 0.1803368802f   /* 0.125 * log2(e) */

// ------------------------------------------------------------------ embed (f32 residual stream)
__global__ __launch_bounds__(256) void embed_kernel(
    const int* __restrict__ tok, const float* __restrict__ emb,
    const float* __restrict__ pe, float* __restrict__ out)
{
  const int total = NTOK * D_MODEL;
  for (int i = blockIdx.x * 256 + threadIdx.x; i < total; i += gridDim.x * 256) {
    int t = i >> 9;
    int d = i & 511;
    int s = t & (SEQ - 1);
    out[i] = emb[(size_t)tok[t] * D_MODEL + d] + pe[(size_t)s * D_MODEL + d];
  }
}

// ------------------------------------------------------------------ pad mask: one u64 per 64 tokens
__global__ __launch_bounds__(64) void padmask_kernel(
    const int* __restrict__ tok, u64* __restrict__ pm)
{
  int b = blockIdx.y, t = blockIdx.x;
  int lane = threadIdx.x;
  u64 m = __ballot(tok[(size_t)b * SEQ + t * 64 + lane] != PAD_ID);
  if (lane == 0) pm[b * (SEQ / 64) + t] = m;
}

// ------------------------------------------------------------------ layernorm: f32 in -> bf16 out
__global__ __launch_bounds__(256) void ln_kernel(
    const float* __restrict__ x, const float* __restrict__ g,
    const float* __restrict__ bb, u16* __restrict__ y)
{
  __shared__ float red[8];
  const size_t row = blockIdx.x;
  const float* xr = x + row * D_MODEL;
  u16* yr = y + row * D_MODEL;
  const int t = threadIdx.x;
  float a0 = xr[t], a1 = xr[t + 256];
  float s = a0 + a1;
  #pragma unroll
  for (int o = 32; o > 0; o >>= 1) s += __shfl_down(s, o, 64);
  int wv = t >> 6, ln = t & 63;
  if (ln == 0) red[wv] = s;
  __syncthreads();
  if (t == 0) red[4] = red[0] + red[1] + red[2] + red[3];
  __syncthreads();
  float mean = red[4] * (1.0f / D_MODEL);
  float d0 = a0 - mean, d1 = a1 - mean;
  float vs = d0 * d0 + d1 * d1;
  #pragma unroll
  for (int o = 32; o > 0; o >>= 1) vs += __shfl_down(vs, o, 64);
  if (ln == 0) red[wv] = vs;
  __syncthreads();
  if (t == 0) red[5] = red[0] + red[1] + red[2] + red[3];
  __syncthreads();
  float inv = rsqrtf(red[5] * (1.0f / D_MODEL) + 1e-5f);
  yr[t]       = f2bf(d0 * inv * g[t]       + bb[t]);
  yr[t + 256] = f2bf(d1 * inv * g[t + 256] + bb[t + 256]);
}

// ------------------------------------------------------------------ f32 -> bf16 elementwise
__global__ __launch_bounds__(256) void cvtbf_kernel(
    const float* __restrict__ s, u16* __restrict__ d, int n)
{
  int i = (blockIdx.x * 256 + threadIdx.x) * 8;
  if (i >= n) return;
  float4 a = *(const float4*)&s[i];
  float4 b = *(const float4*)&s[i + 4];
  u32 p0 = (u32)f2bf(a.x) | ((u32)f2bf(a.y) << 16);
  u32 p1 = (u32)f2bf(a.z) | ((u32)f2bf(a.w) << 16);
  u32 p2 = (u32)f2bf(b.x) | ((u32)f2bf(b.y) << 16);
  u32 p3 = (u32)f2bf(b.z) | ((u32)f2bf(b.w) << 16);
  uint4 o; o.x = p0; o.y = p1; o.z = p2; o.w = p3;
  *(uint4*)&d[i] = o;
}

// ------------------------------------------------------------------ transpose+convert: src f32 [K][N] -> dst bf16 [N][K]
__global__ __launch_bounds__(256) void tconv_kernel(
    const float* __restrict__ src, u16* __restrict__ dst, int K, int N)
{
  __shared__ float tile[64][65];
  const size_t z = blockIdx.z;
  src += z * (size_t)K * N;
  dst += z * (size_t)K * N;
  const int n0 = blockIdx.x * 64, k0 = blockIdx.y * 64;
  const int t = threadIdx.x;
  const int cr = t >> 4, cc = (t & 15) * 4;
  #pragma unroll
  for (int it = 0; it < 4; ++it) {
    int kr = cr + it * 16;
    float4 v = *(const float4*)&src[(size_t)(k0 + kr) * N + n0 + cc];
    tile[kr][cc] = v.x; tile[kr][cc + 1] = v.y; tile[kr][cc + 2] = v.z; tile[kr][cc + 3] = v.w;
  }
  __syncthreads();
  #pragma unroll
  for (int it = 0; it < 4; ++it) {
    int nr = cr + it * 16;
    u32 lo = (u32)f2bf(tile[cc + 0][nr]) | ((u32)f2bf(tile[cc + 1][nr]) << 16);
    u32 hi = (u32)f2bf(tile[cc + 2][nr]) | ((u32)f2bf(tile[cc + 3][nr]) << 16);
    uint2 pk; pk.x = lo; pk.y = hi;
    *(uint2*)&dst[(size_t)(n0 + nr) * K + k0 + cc] = pk;
  }
}

// ------------------------------------------------------------------ bf16 MFMA GEMM: C[M,N] = A[M,K] @ Wt[N,K]^T + bias
// MODE 0: f32 out, 1: f32 out + res, 2: bf16 out, 3: bf16 out + relu
// MODE 4: qkv  (z==2 -> V-transpose epilogue into vtOut)     [BN==64]
// MODE 5: crosskv (MAP==1 weight map; odd z -> V-transpose)  [BN==64]
// BM x BN tile, BK=64, 4 waves (2x2). XOR-swizzled LDS.
template<int MODE, int BM, int BN, int MAP>
__global__ __launch_bounds__(256, 2) void mm_kernel(
    const u16* __restrict__ A, const u16* __restrict__ Wt,
    const float* __restrict__ bias, const float* __restrict__ res,
    void* __restrict__ Cout, u16* __restrict__ vtOut,
    int M, int N, int K,
    long long wStride, long long bStride, long long cStride)
{
  constexpr int MI = BM / 32;
  constexpr int NI = BN / 32;
  __shared__ u16 sh[(BM + BN) * 64];
  u16* As = sh;
  u16* Bs = sh + BM * 64;
  const int z = blockIdx.z;
  size_t wOff, bOff;
  if (MAP == 1) {
    wOff = (size_t)(z >> 1) * 4 * 262144 + (size_t)(1 + (z & 1)) * 262144;
    bOff = (size_t)(z >> 1) * 4 * 512 + (size_t)(1 + (z & 1)) * 512;
  } else {
    wOff = (size_t)z * wStride;
    bOff = (size_t)z * bStride;
  }
  Wt += wOff;
  bias += bOff;
  const int bm = blockIdx.y * BM, bn = blockIdx.x * BN;
  const int tid = threadIdx.x, lane = tid & 63, w = tid >> 6;
  const int wm = w >> 1, wn = w & 1;
  const int l15 = lane & 15, l4 = lane >> 4;
  const int wrow0 = wm * (BM / 2), wcol0 = wn * (BN / 2);
  const u16* aBase = A  + (size_t)bm * K;
  const u16* bBase = Wt + (size_t)bn * K;
  f32x4 acc[MI][NI] = {};

  for (int k0 = 0; k0 < K; k0 += 64) {
    #pragma unroll
    for (int i = 0; i < BM / 32; ++i) {
      int lin = i * 256 + tid;
      int r = lin >> 3, sp = lin & 7;
      gload16(aBase + (size_t)r * K + k0 + ((sp ^ (r & 7)) * 8), &As[(i * 256 + w * 64) * 8]);
    }
    #pragma unroll
    for (int i = 0; i < BN / 32; ++i) {
      int lin = i * 256 + tid;
      int r = lin >> 3, sp = lin & 7;
      gload16(bBase + (size_t)r * K + k0 + ((sp ^ (r & 7)) * 8), &Bs[(i * 256 + w * 64) * 8]);
    }
    __syncthreads();
    #pragma unroll
    for (int ks = 0; ks < 2; ++ks) {
      s16x8 af[MI], bf[NI];
      #pragma unroll
      for (int mi = 0; mi < MI; ++mi) {
        int rr = wrow0 + mi * 16 + l15;
        af[mi] = *(const s16x8*)&As[(rr << 6) + (((ks * 4 + l4) ^ (rr & 7)) << 3)];
      }
      #pragma unroll
      for (int ni = 0; ni < NI; ++ni) {
        int rr = wcol0 + ni * 16 + l15;
        bf[ni] = *(const s16x8*)&Bs[(rr << 6) + (((ks * 4 + l4) ^ (rr & 7)) << 3)];
      }
      #pragma unroll
      for (int mi = 0; mi < MI; ++mi)
        #pragma unroll
        for (int ni = 0; ni < NI; ++ni)
          acc[mi][ni] = __builtin_amdgcn_mfma_f32_16x16x32_bf16(af[mi], bf[ni], acc[mi][ni], 0, 0, 0);
    }
    __syncthreads();
  }

  const bool vpath = (MODE == 4 && z == 2) || (MODE == 5 && (z & 1) == 1);
  if (vpath) {
    // BN==64: this block covers tokens [bm,bm+64) x head (bn>>6), full d in [0,64).
    u16* TT = sh;   // stride 72 u16; As/Bs dead (post-barrier)
    #pragma unroll
    for (int mi = 0; mi < MI; ++mi)
      #pragma unroll
      for (int ni = 0; ni < NI; ++ni)
        #pragma unroll
        for (int r = 0; r < 4; ++r) {
          int rowl = wrow0 + mi * 16 + l4 * 4 + r;   // local token
          int coll = wcol0 + ni * 16 + l15;          // local d
          TT[coll * 72 + rowl] = f2bf(acc[mi][ni][r] + bias[bn + coll]);
        }
    __syncthreads();
    const int b = bm >> 11, s0loc = bm & 2047, h = bn >> 6;
    const int layer = (MODE == 5) ? (z >> 1) : 0;
    u16* vbase = vtOut + (size_t)layer * ((size_t)NTOK * D_MODEL)
               + ((size_t)(b * NHEAD + h) * 64) * SEQ;
    int d = tid >> 2, sc = (tid & 3) * 16;
    s16x8 v0 = *(const s16x8*)&TT[d * 72 + sc];
    s16x8 v1 = *(const s16x8*)&TT[d * 72 + sc + 8];
    *(s16x8*)(vbase + (size_t)d * SEQ + s0loc + sc) = v0;
    *(s16x8*)(vbase + (size_t)d * SEQ + s0loc + sc + 8) = v1;
    return;
  }

  const int zi = (MAP == 1) ? (z >> 1) : z;
  #pragma unroll
  for (int ni = 0; ni < NI; ++ni) {
    int col = bn + wcol0 + ni * 16 + l15;
    float bb = bias[col];
    #pragma unroll
    for (int mi = 0; mi < MI; ++mi) {
      #pragma unroll
      for (int r = 0; r < 4; ++r) {
        int row = bm + wrow0 + mi * 16 + l4 * 4 + r;
        size_t off = (size_t)zi * cStride + (size_t)row * N + col;
        float v = acc[mi][ni][r] + bb;
        if (MODE == 1) v += res[(size_t)row * N + col];
        if (MODE == 3) v = fmaxf(v, 0.0f);
        if (MODE <= 1) ((float*)Cout)[off] = v;
        else           ((u16*)Cout)[off] = f2bf(v);
      }
    }
  }
}

// ------------------------------------------------------------------ flash attention, bf16 MFMA, KVBLK=128, dbuf prefetch
// grid (SEQ/64, H, B), 4 waves; wave w owns q-rows [qt+16w, qt+16w+16)
template<int CAUSAL>
__global__ __launch_bounds__(256, 2) void fattn_kernel(
    const u16* __restrict__ Qg, const u16* __restrict__ Kg,
    const u16* __restrict__ Vt, const u64* __restrict__ padm,
    u16* __restrict__ Og)
{
  __shared__ u16 Ks[2][128 * 64];
  __shared__ u16 Vs[2][64 * 128];
  __shared__ u16 Ps[4][16 * 128];
  const int qtile = CAUSAL ? (int)(gridDim.x - 1 - blockIdx.x) : (int)blockIdx.x;
  const int qt = qtile * 64;
  const int h = blockIdx.y, b = blockIdx.z;
  const int tid = threadIdx.x, lane = tid & 63, w = tid >> 6;
  const int l15 = lane & 15, l4 = lane >> 4;
  const int hoff = h * 64;
  const u16* Kbase = Kg + (size_t)(b * SEQ) * D_MODEL + hoff;
  const u16* Vbase = Vt + (size_t)(b * NHEAD + h) * 64 * SEQ;
  const u64* pmb = padm + b * (SEQ / 64);

  s16x8 aq[2];
  {
    const u16* qp = Qg + (size_t)(b * SEQ + qt + w * 16 + l15) * D_MODEL + hoff + l4 * 8;
    aq[0] = *(const s16x8*)qp;
    aq[1] = *(const s16x8*)(qp + 32);
  }

  f32x4 oacc[4] = {};
  float mrow[4] = {-1e30f, -1e30f, -1e30f, -1e30f};
  float lrow[4] = {0.f, 0.f, 0.f, 0.f};
  const int nt = CAUSAL ? (qt >> 7) + 1 : SEQ / 128;

  #define STAGE(KV0, BUF)                                                              \
    {                                                                                  \
      _Pragma("unroll")                                                                \
      for (int it = 0; it < 4; ++it) {                                                 \
        int lin = it * 256 + tid;                                                      \
        int rr = lin >> 3, sp = lin & 7;                                               \
        gload16(Kbase + (size_t)((KV0) + rr) * D_MODEL + ((sp ^ (rr & 7)) * 8),        \
                &Ks[BUF][(it * 256 + w * 64) * 8]);                                    \
      }                                                                                \
      _Pragma("unroll")                                                                \
      for (int it = 0; it < 4; ++it) {                                                 \
        int lin = it * 256 + tid;                                                      \
        int rr = lin >> 4, ko = lin & 15;                                              \
        gload16(Vbase + (size_t)rr * SEQ + (KV0) + ((ko ^ (rr & 15)) * 8),             \
                &Vs[BUF][(it * 256 + w * 64) * 8]);                                    \
      }                                                                                \
    }

  STAGE(0, 0);
  __syncthreads();

  for (int kt = 0; kt < nt; ++kt) {
    const int kv0 = kt * 128;
    const int cur = kt & 1;
    if (kt + 1 < nt) STAGE(kv0 + 128, cur ^ 1);

    f32x4 sac[8] = {};
    #pragma unroll
    for (int ks = 0; ks < 2; ++ks)
      #pragma unroll
      for (int jn = 0; jn < 8; ++jn) {
        int rr = jn * 16 + l15;
        s16x8 bk = *(const s16x8*)&Ks[cur][(rr << 6) + (((ks * 4 + l4) ^ (rr & 7)) << 3)];
        sac[jn] = __builtin_amdgcn_mfma_f32_16x16x32_bf16(aq[ks], bk, sac[jn], 0, 0, 0);
      }

    const u64 m0 = pmb[(kv0 >> 6)];
    const u64 m1 = pmb[(kv0 >> 6) + 1];
    const bool lastC = CAUSAL && (kt == nt - 1);
    if (((m0 & m1) != ~0ull) || lastC) {
      #pragma unroll
      for (int jn = 0; jn < 8; ++jn) {
        int kvg = kv0 + jn * 16 + l15;
        u64 mm = (jn < 4) ? m0 : m1;
        bool okp = (mm >> ((jn & 3) * 16 + l15)) & 1;
        #pragma unroll
        for (int r = 0; r < 4; ++r) {
          int qg = qt + w * 16 + l4 * 4 + r;
          bool ok = okp && (!CAUSAL || kvg <= qg);
          if (!ok) sac[jn][r] = -1e30f;
        }
      }
    }

    float mx[4];
    #pragma unroll
    for (int r = 0; r < 4; ++r) {
      float m = fmaxf(fmaxf(fmaxf(sac[0][r], sac[1][r]), fmaxf(sac[2][r], sac[3][r])),
                      fmaxf(fmaxf(sac[4][r], sac[5][r]), fmaxf(sac[6][r], sac[7][r])));
      #pragma unroll
      for (int o = 1; o < 16; o <<= 1) m = fmaxf(m, __shfl_xor(m, o, 16));
      mx[r] = m;
    }
    float growth = fmaxf(fmaxf(mx[0] - mrow[0], mx[1] - mrow[1]),
                         fmaxf(mx[2] - mrow[2], mx[3] - mrow[3]));
    if (__any(growth > 64.0f)) {
      #pragma unroll
      for (int r = 0; r < 4; ++r) {
        float mn = fmaxf(mrow[r], mx[r]);
        float sc = exp2i((mrow[r] - mn) * CEXP);
        mrow[r] = mn;
        lrow[r] *= sc;
        #pragma unroll
        for (int jn = 0; jn < 4; ++jn) oacc[jn][r] *= sc;
      }
    }

    #pragma unroll
    for (int r = 0; r < 4; ++r) {
      const int prow = l4 * 4 + r;
      float rs = 0.f;
      #pragma unroll
      for (int jn = 0; jn < 8; ++jn) {
        float pv = exp2i((sac[jn][r] - mrow[r]) * CEXP);
        rs += pv;
        int g = ((jn * 2 + (l15 >> 3)) ^ prow) & 15;
        Ps[w][prow * 128 + g * 8 + (l15 & 7)] = f2bf(pv);
      }
      #pragma unroll
      for (int o = 1; o < 16; o <<= 1) rs += __shfl_xor(rs, o, 16);
      lrow[r] += rs;
    }

    #pragma unroll
    for (int kslot = 0; kslot < 4; ++kslot) {
      s16x8 pa = *(const s16x8*)&Ps[w][l15 * 128 + ((((kslot * 4 + l4) ^ l15) & 15) << 3)];
      #pragma unroll
      for (int jn = 0; jn < 4; ++jn) {
        int rr = jn * 16 + l15;
        s16x8 bv = *(const s16x8*)&Vs[cur][(rr << 7) + (((kslot * 4 + l4) ^ (rr & 15)) << 3)];
        oacc[jn] = __builtin_amdgcn_mfma_f32_16x16x32_bf16(pa, bv, oacc[jn], 0, 0, 0);
      }
    }
    __syncthreads();
  }
  #undef STAGE

  float inv[4];
  #pragma unroll
  for (int r = 0; r < 4; ++r) inv[r] = 1.0f / lrow[r];
  #pragma unroll
  for (int jn = 0; jn < 4; ++jn)
    #pragma unroll
    for (int r = 0; r < 4; ++r)
      Og[(size_t)(b * SEQ + qt + w * 16 + l4 * 4 + r) * D_MODEL + hoff + jn * 16 + l15] =
          f2bf(oacc[jn][r] * inv[r]);
}

// ------------------------------------------------------------------ host
extern "C" void kernel_launch(void* const* d_in, const int* in_sizes, int n_in,
                              void* d_out, int out_size, void* d_ws, size_t ws_size,
                              hipStream_t stream)
{
  const int*   src        = (const int*)  d_in[0];
  const int*   tgt        = (const int*)  d_in[1];
  const float* src_emb    = (const float*)d_in[2];
  const float* tgt_emb    = (const float*)d_in[3];
  const float* pe         = (const float*)d_in[4];
  const float* enc_attn_w = (const float*)d_in[5];
  const float* enc_attn_b = (const float*)d_in[6];
  const float* enc_ff_w1  = (const float*)d_in[7];
  const float* enc_ff_b1  = (const float*)d_in[8];
  const float* enc_ff_w2  = (const float*)d_in[9];
  const float* enc_ff_b2  = (const float*)d_in[10];
  const float* enc_ln_g   = (const float*)d_in[11];
  const float* enc_ln_bb  = (const float*)d_in[12];
  const float* dec_self_w = (const float*)d_in[13];
  const float* dec_self_b = (const float*)d_in[14];
  const float* dec_src_w  = (const float*)d_in[15];
  const float* dec_src_b  = (const float*)d_in[16];
  const float* dec_ff_w1  = (const float*)d_in[17];
  const float* dec_ff_b1  = (const float*)d_in[18];
  const float* dec_ff_w2  = (const float*)d_in[19];
  const float* dec_ff_b2  = (const float*)d_in[20];
  const float* dec_ln_g   = (const float*)d_in[21];
  const float* dec_ln_bb  = (const float*)d_in[22];
  const float* fin_ln_g   = (const float*)d_in[23];
  const float* fin_ln_b   = (const float*)d_in[24];
  const float* fc_w       = (const float*)d_in[25];
  const float* fc_b       = (const float*)d_in[26];
  float* out = (float*)d_out;

  const size_t DD = (size_t)D_MODEL * D_MODEL;
  const size_t FD = (size_t)D_MODEL * DFF_;
  const size_t TD = (size_t)NTOK * D_MODEL;

  // ---- scratch in d_out (all dead before the final GEMM writes d_out) ----
  char* ob = (char*)d_out;
  size_t off = 0;
  auto alloco = [&](size_t bytes) { void* p = ob + off; off += (bytes + 255) & ~(size_t)255; return p; };
  u16* wt_enc_attn = (u16*)alloco(24 * DD * 2);
  u16* wt_dec_self = (u16*)alloco(24 * DD * 2);
  u16* wt_dec_src  = (u16*)alloco(24 * DD * 2);
  u16* wt_enc_ff1  = (u16*)alloco(6 * FD * 2);
  u16* wt_enc_ff2  = (u16*)alloco(6 * FD * 2);
  u16* wt_dec_ff1  = (u16*)alloco(6 * FD * 2);
  u16* wt_dec_ff2  = (u16*)alloco(6 * FD * 2);
  u16* qb   = (u16*)alloco(2 * TD * 2);             // q,k contiguous
  u16* kb   = qb + TD;
  u16* vtb  = (u16*)alloco(TD * 2);                 // self-attn V^T [B*H][64][SEQ]
  u16* aob  = (u16*)alloco(TD * 2);
  u16* hbb  = (u16*)alloco((size_t)NTOK * DFF_ * 2);
  u16* memb = (u16*)alloco(TD * 2);
  u16* ckb  = (u16*)alloco(6 * TD * 2);             // cross K, all layers
  u16* cvtb = (u16*)alloco(6 * TD * 2);             // cross V^T, all layers

  // ---- mandatory ws (live during final GEMM) ----
  char* wsb = (char*)d_ws;
  u16*   fcwt = (u16*)wsb;
  size_t wo = ((size_t)VOCAB * D_MODEL * 2 + 255) & ~(size_t)255;
  float* xe  = (float*)(wsb + wo); wo += TD * 4;
  float* yd  = (float*)(wsb + wo); wo += TD * 4;
  u16*   x2b = (u16*)(wsb + wo);   wo += TD * 2;
  u64*   pmS = (u64*)(wsb + wo);   wo += 1024;
  u64*   pmT = (u64*)(wsb + wo);

  dim3 blk(256);
  dim3 gN512(8, 64, 1), gQKV(8, 64, 3), gCKV(8, 64, 12);
  dim3 gFF1(16, 32, 1), gFF2(8, 64, 1), gFC(250, 32, 1);
  dim3 gAttn(SEQ / 64, NHEAD, BATCH);
  dim3 gPM(SEQ / 64, BATCH);
  const long long llDD = (long long)DD, llTD = (long long)TD;

  // ---- one-time prep ----
  padmask_kernel<<<gPM, dim3(64), 0, stream>>>(src, pmS);
  padmask_kernel<<<gPM, dim3(64), 0, stream>>>(tgt, pmT);
  tconv_kernel<<<dim3(8, 8, 24), blk, 0, stream>>>(enc_attn_w, wt_enc_attn, 512, 512);
  tconv_kernel<<<dim3(8, 8, 24), blk, 0, stream>>>(dec_self_w, wt_dec_self, 512, 512);
  tconv_kernel<<<dim3(8, 8, 24), blk, 0, stream>>>(dec_src_w,  wt_dec_src,  512, 512);
  tconv_kernel<<<dim3(32, 8, 6), blk, 0, stream>>>(enc_ff_w1, wt_enc_ff1, 512, 2048);
  tconv_kernel<<<dim3(8, 32, 6), blk, 0, stream>>>(enc_ff_w2, wt_enc_ff2, 2048, 512);
  tconv_kernel<<<dim3(32, 8, 6), blk, 0, stream>>>(dec_ff_w1, wt_dec_ff1, 512, 2048);
  tconv_kernel<<<dim3(8, 32, 6), blk, 0, stream>>>(dec_ff_w2, wt_dec_ff2, 2048, 512);
  tconv_kernel<<<dim3(500, 8, 1), blk, 0, stream>>>(fc_w, fcwt, 512, VOCAB);

  // ---- encoder ----
  embed_kernel<<<dim3(2048), blk, 0, stream>>>(src, src_emb, pe, xe);
  for (int l = 0; l < NLAYER; ++l) {
    ln_kernel<<<dim3(NTOK), blk, 0, stream>>>(xe, enc_ln_g + (size_t)(l * 2 + 0) * D_MODEL,
                                              enc_ln_bb + (size_t)(l * 2 + 0) * D_MODEL, x2b);
    mm_kernel<4, 64, 64, 0><<<gQKV, blk, 0, stream>>>(x2b, wt_enc_attn + (size_t)l * 4 * DD,
        enc_attn_b + (size_t)l * 4 * D_MODEL, nullptr, qb, vtb, NTOK, 512, 512, llDD, D_MODEL, llTD);
    fattn_kernel<0><<<gAttn, blk, 0, stream>>>(qb, kb, vtb, pmS, aob);
    mm_kernel<1, 64, 64, 0><<<gN512, blk, 0, stream>>>(aob, wt_enc_attn + (size_t)(l * 4 + 3) * DD,
        enc_attn_b + (size_t)(l * 4 + 3) * D_MODEL, xe, xe, nullptr, NTOK, 512, 512, 0, 0, 0);
    ln_kernel<<<dim3(NTOK), blk, 0, stream>>>(xe, enc_ln_g + (size_t)(l * 2 + 1) * D_MODEL,
                                              enc_ln_bb + (size_t)(l * 2 + 1) * D_MODEL, x2b);
    mm_kernel<3, 128, 128, 0><<<gFF1, blk, 0, stream>>>(x2b, wt_enc_ff1 + (size_t)l * FD,
        enc_ff_b1 + (size_t)l * DFF_, nullptr, hbb, nullptr, NTOK, DFF_, 512, 0, 0, 0);
    mm_kernel<1, 64, 64, 0><<<gFF2, blk, 0, stream>>>(hbb, wt_enc_ff2 + (size_t)l * FD,
        enc_ff_b2 + (size_t)l * D_MODEL, xe, xe, nullptr, NTOK, 512, DFF_, 0, 0, 0);
  }
  cvtbf_kernel<<<dim3(1024), blk, 0, stream>>>(xe, memb, NTOK * D_MODEL);

  // ---- all 6 decoder layers' cross K / V^T in one batched launch ----
  mm_kernel<5, 64, 64, 1><<<gCKV, blk, 0, stream>>>(memb, wt_dec_src, dec_src_b, nullptr,
      ckb, cvtb, NTOK, 512, 512, 0, 0, llTD);

  // ---- decoder ----
  embed_kernel<<<dim3(2048), blk, 0, stream>>>(tgt, tgt_emb, pe, yd);
  for (int l = 0; l < NLAYER; ++l) {
    const u16* Ws = wt_dec_self + (size_t)l * 4 * DD;
    const u16* Wc = wt_dec_src + (size_t)l * 4 * DD;
    const float* bs  = dec_self_b + (size_t)l * 4 * D_MODEL;
    const float* bcb = dec_src_b + (size_t)l * 4 * D_MODEL;
    // self-attention (causal + tgt pad mask)
    ln_kernel<<<dim3(NTOK), blk, 0, stream>>>(yd, dec_ln_g + (size_t)(l * 3 + 0) * D_MODEL,
                                              dec_ln_bb + (size_t)(l * 3 + 0) * D_MODEL, x2b);
    mm_kernel<4, 64, 64, 0><<<gQKV, blk, 0, stream>>>(x2b, Ws, bs, nullptr, qb, vtb,
                                                      NTOK, 512, 512, llDD, D_MODEL, llTD);
    fattn_kernel<1><<<gAttn, blk, 0, stream>>>(qb, kb, vtb, pmT, aob);
    mm_kernel<1, 64, 64, 0><<<gN512, blk, 0, stream>>>(aob, Ws + 3 * DD, bs + 3 * D_MODEL, yd, yd,
                                                       nullptr, NTOK, 512, 512, 0, 0, 0);
    // cross-attention (src pad mask); K/V precomputed
    ln_kernel<<<dim3(NTOK), blk, 0, stream>>>(yd, dec_ln_g + (size_t)(l * 3 + 1) * D_MODEL,
                                              dec_ln_bb + (size_t)(l * 3 + 1) * D_MODEL, x2b);
    mm_kernel<2, 64, 64, 0><<<gN512, blk, 0, stream>>>(x2b, Wc, bcb, nullptr, qb, nullptr,
                                                       NTOK, 512, 512, 0, 0, 0);
    fattn_kernel<0><<<gAttn, blk, 0, stream>>>(qb, ckb + (size_t)l * TD, cvtb + (size_t)l * TD,
                                               pmS, aob);
    mm_kernel<1, 64, 64, 0><<<gN512, blk, 0, stream>>>(aob, Wc + 3 * DD, bcb + 3 * D_MODEL, yd, yd,
                                                       nullptr, NTOK, 512, 512, 0, 0, 0);
    // feed-forward
    ln_kernel<<<dim3(NTOK), blk, 0, stream>>>(yd, dec_ln_g + (size_t)(l * 3 + 2) * D_MODEL,
                                              dec_ln_bb + (size_t)(l * 3 + 2) * D_MODEL, x2b);
    mm_kernel<3, 128, 128, 0><<<gFF1, blk, 0, stream>>>(x2b, wt_dec_ff1 + (size_t)l * FD,
        dec_ff_b1 + (size_t)l * DFF_, nullptr, hbb, nullptr, NTOK, DFF_, 512, 0, 0, 0);
    mm_kernel<1, 64, 64, 0><<<gFF2, blk, 0, stream>>>(hbb, wt_dec_ff2 + (size_t)l * FD,
        dec_ff_b2 + (size_t)l * D_MODEL, yd, yd, nullptr, NTOK, 512, DFF_, 0, 0, 0);
  }

  // ---- head ----
  ln_kernel<<<dim3(NTOK), blk, 0, stream>>>(yd, fin_ln_g, fin_ln_b, x2b);
  mm_kernel<0, 128, 128, 0><<<gFC, blk, 0, stream>>>(x2b, fcwt, fc_b, nullptr, out, nullptr,
                                                     NTOK, VOCAB, 512, 0, 0, 0);

  (void)in_sizes; (void)n_in; (void)out_size; (void)ws_size;
}